// Round 8
// baseline (21418.939 us; speedup 1.0000x reference)
//
#include <hip/hip_runtime.h>
#include <stdint.h>

// ---------------------------------------------------------------------------
// VQ-VAE forward on MI355X. Round 12: igemm B-operand -> direct global
// register loads. R11's dec1 (top dispatch, 173us) was LDS-occupancy-capped:
// 40KB/block -> 3 blocks/CU (Occ 31%), MfmaUtil 16%, no pipe busy. ldsB was
// pure overhead: B panels are <=1MB L2-resident, and for 256x64 all 4 waves
// read the SAME B cols (4x LDS redundancy). R12: B fragments loaded straight
// from global into registers, double-buffered one K-step ahead (unroll-2 so
// the parity index is compile-time, rule #20). LDS: 40->32KB (256x64),
// 32->16KB (128x128) -> ~5/6+ blocks/CU. The per-kstep barrier's vmcnt drain
// already covers the B prefetch. Numerics bit-identical. Rest unchanged.
// ---------------------------------------------------------------------------

typedef unsigned short bfraw;
typedef __attribute__((ext_vector_type(8))) short s16x8;
typedef __attribute__((ext_vector_type(4))) float f32x4;

__device__ __forceinline__ float bflo(unsigned int u) {
    union { unsigned int i; float f; } v; v.i = u << 16; return v.f;
}
__device__ __forceinline__ float bfhi(unsigned int u) {
    union { unsigned int i; float f; } v; v.i = u & 0xFFFF0000u; return v.f;
}
__device__ __forceinline__ bfraw f2bf(float f) {
    union { float f; unsigned int i; } v; v.f = f;
    unsigned int r = v.i + 0x7FFFu + ((v.i >> 16) & 1u);   // RNE
    return (bfraw)(r >> 16);
}

// async 16B global->LDS. LDS dest: wave-uniform base + lane*16; global src per-lane.
__device__ __forceinline__ void gl_lds16(const void* g, void* l) {
    auto gp = reinterpret_cast<const __attribute__((address_space(1))) unsigned int*>(
        reinterpret_cast<uintptr_t>(g));
    auto lp = reinterpret_cast<__attribute__((address_space(3))) unsigned int*>(
        reinterpret_cast<uintptr_t>(l));
    __builtin_amdgcn_global_load_lds(gp, lp, 16, 0, 0);
}

// --- weight transform (bf16, [co][tap][ci]) for MFMA convs (B as [n][k]);
//     with KH=KW=1 also converts emb[512][256] to bf16 B layout.
__global__ void wtb_kernel(const float* __restrict__ w, bfraw* __restrict__ wt,
                           int Cout, int Cin, int KH, int KW, int transposed) {
    int n = Cout * Cin * KH * KW;
    int NT = KH * KW;
    for (int i = blockIdx.x * blockDim.x + threadIdx.x; i < n; i += gridDim.x * blockDim.x) {
        int ci = i % Cin; int t = i / Cin;
        int tap = t % NT; int co = t / NT;
        int kh = tap / KW, kw = tap % KW;
        float v = transposed ? w[(((long)ci * Cout + co) * KH + kh) * KW + kw]
                             : w[(((long)co * Cin + ci) * KH + kh) * KW + kw];
        wt[i] = f2bf(v);
    }
}

// --- dec2 weight pack: wb2[16][576] bf16, B[co][tap*64+ci]; rows 3..15 zero.
//     convT k3 p1 == conv with wf[co][ci][kh'][kw'] = w[ci][co][2-kh'][2-kw'].
__global__ void wb2_kernel(const float* __restrict__ w, bfraw* __restrict__ wt) {
    int i = blockIdx.x * 256 + threadIdx.x;   // 9216 = 16*576
    if (i >= 9216) return;
    int ci = i & 63; int t = i >> 6;          // t = co*9 + tap
    int tap = t % 9, co = t / 9;
    bfraw v = 0;
    if (co < 3) {
        int kh = 2 - tap / 3, kw = 2 - tap % 3;
        v = f2bf(w[(((long)ci * 3 + co) * 3 + kh) * 3 + kw]);
    }
    wt[(long)co * 576 + tap * 64 + ci] = v;
}

// --- enc1 weight pack: wb1[co][k64], k=(kh*4+kw)*3+ci (48 real, 16 zero)
__global__ void wb1_kernel(const float* __restrict__ w, bfraw* __restrict__ wt) {
    int i = blockIdx.x * 256 + threadIdx.x;
    if (i >= 4096) return;
    int k = i & 63, co = i >> 6;
    bfraw v = 0;
    if (k < 48) {
        int ci = k % 3, tap = k / 3, kh = tap >> 2, kw = tap & 3;
        v = f2bf(w[(((long)co * 3 + ci) * 4 + kh) * 4 + kw]);
    }
    wt[(long)co * 64 + k] = v;
}

// --- enc1 im2col: x NCHW fp32 -> A0[pos][64] bf16 (48 patch vals + 16 zeros)
__global__ __launch_bounds__(256) void xpack_kernel(const float* __restrict__ x,
                                                    bfraw* __restrict__ a0) {
    int pos = blockIdx.x * 256 + threadIdx.x;        // 262144
    int ow = pos & 127, oh = (pos >> 7) & 127, n = pos >> 14;
    __align__(16) bfraw v[64];
#pragma unroll
    for (int i = 0; i < 64; ++i) v[i] = 0;
#pragma unroll
    for (int kh = 0; kh < 4; ++kh) {
        int ih = 2 * oh - 1 + kh; if ((unsigned)ih >= 256u) continue;
#pragma unroll
        for (int kw = 0; kw < 4; ++kw) {
            int iw = 2 * ow - 1 + kw; if ((unsigned)iw >= 256u) continue;
#pragma unroll
            for (int ci = 0; ci < 3; ++ci)
                v[(kh * 4 + kw) * 3 + ci] =
                    f2bf(x[(((long)n * 3 + ci) * 256 + ih) * 256 + iw]);
        }
    }
    uint4* dst = (uint4*)(a0 + (long)pos * 64);
    const uint4* src = (const uint4*)v;
#pragma unroll
    for (int i = 0; i < 8; ++i) dst[i] = src[i];
}

// --- emb row norms
__global__ void embsq_kernel(const float* __restrict__ emb, float* __restrict__ esq) {
    int k = blockIdx.x, lane = threadIdx.x;
    float s = 0.f;
    for (int d = lane; d < 256; d += 64) { float v = emb[k * 256 + d]; s += v * v; }
    for (int o = 32; o; o >>= 1) s += __shfl_down(s, o, 64);
    if (lane == 0) esq[k] = s;
}

// ---------------------------------------------------------------------------
// MFMA implicit GEMM. C[MxN] = A[MxK]*B[KxN]. A: 2-phase LDS double-buffer
// (STAGE(t+1) before compute(t), one barrier per K-step). B: direct global
// register loads (L2-resident panels), double-buffered one K-step ahead;
// unroll-2 keeps the parity index compile-time. blockIdx.z = convT parity
// class; XCD-bijective blockM swizzle.
// ---------------------------------------------------------------------------
template<int BM, int BN, int WM, int WN, bool TR, bool RELU, bool OUTF32, bool DUALB>
__global__ __launch_bounds__(256) void igemm_kernel(
    const bfraw* __restrict__ in, const bfraw* __restrict__ wt,
    const float* __restrict__ bias, void* __restrict__ outv,
    bfraw* __restrict__ outb, const bfraw* __restrict__ zp,
    int Hin, int Win, int Cin, int sf, int NTW, int Ksteps,
    int lw, int lh, int N, int KW, int pad,
    unsigned long long pk0, unsigned long long pk1,
    unsigned long long pk2, unsigned long long pk3)
{
    constexpr int APASS = BM / 64;
    __shared__ __align__(16) bfraw ldsA[2][BM * 32];
    const int tid = threadIdx.x, lane = tid & 63, wv = tid >> 6;
    const int wm = wv / WN, wn = wv % WN;
    const int lrow = lane >> 2, lkof = (lane & 3) * 8;
    const int n0 = blockIdx.y * BN;
    const int Wm1 = (1 << lw) - 1, Hm1 = (1 << lh) - 1;
    // XCD-bijective swizzle (gridDim.x % 8 == 0 for all launches)
    const int bid = blockIdx.x;
    const int blockM = (bid & 7) * ((int)gridDim.x >> 3) + (bid >> 3);
    // convT parity class
    const int cls = blockIdx.z;
    const unsigned long long pack = (cls == 0) ? pk0 : (cls == 1) ? pk1
                                  : (cls == 2) ? pk2 : pk3;
    const int py = cls >> 1, px = cls & 1;

    const int quad = lane >> 4, r16 = lane & 15;

    long baseA[APASS]; int ihb[APASS], iwb[APASS];
#pragma unroll
    for (int p = 0; p < APASS; ++p) {
        int m = p * 64 + wv * 16 + lrow;
        int pos = blockM * BM + m;
        int ow = pos & Wm1; int t = pos >> lw;
        int oh = t & Hm1;   int nb = t >> lh;
        ihb[p] = oh * sf; iwb[p] = ow * sf;
        baseA[p] = ((long)(nb * Hin + ihb[p]) * Win + iwb[p]) * (long)Cin + lkof;
    }
    // per-lane B row bases (col = wn*64 + j*16 + r16), k-offset added per kstep
    long baseB[4];
#pragma unroll
    for (int j = 0; j < 4; ++j)
        baseB[j] = (long)(n0 + wn * 64 + j * 16 + r16) * ((long)NTW * Cin) + quad * 8;

    f32x4 acc[4][4];
#pragma unroll
    for (int i = 0; i < 4; ++i)
#pragma unroll
        for (int j = 0; j < 4; ++j) acc[i][j] = (f32x4)0.f;

    int ci0 = 0, tslot = 0, dy, dx, wk;
    if (TR) {
        unsigned e = (unsigned)pack & 0xFFFFu;
        dy = (int)((e >> 8) & 3) - 1; dx = (int)((e >> 4) & 3) - 1; wk = (int)(e & 15u);
    } else { dy = -pad; dx = -pad; wk = 0; }

    s16x8 bf[2][4];

    // ---- stage helper (issues APASS async loads into buf) ----
    auto stage = [&](int buf) {
        long offA = ((long)(dy * Win + dx)) * Cin + ci0;
#pragma unroll
        for (int p = 0; p < APASS; ++p) {
            int ih = ihb[p] + dy, iw = iwb[p] + dx;
            bool ok = ((unsigned)ih < (unsigned)Hin) & ((unsigned)iw < (unsigned)Win);
            const bfraw* g = ok ? (in + baseA[p] + offA) : (zp + lkof);
            gl_lds16(g, &ldsA[buf][(p * 64 + wv * 16) * 32]);
        }
    };
    auto loadB = [&](int b) {
        long offB = (long)wk * Cin + ci0;
#pragma unroll
        for (int j = 0; j < 4; ++j)
            bf[b][j] = *(const s16x8*)(wt + baseB[j] + offB);
    };
    auto advance = [&]() {
        ci0 += 32;
        if (ci0 == Cin) {
            ci0 = 0; ++tslot;
            if (TR) {
                unsigned e = (unsigned)(pack >> ((tslot & 3) * 16)) & 0xFFFFu;
                dy = (int)((e >> 8) & 3) - 1; dx = (int)((e >> 4) & 3) - 1; wk = (int)(e & 15u);
            } else { ++wk; ++dx; if (dx == KW - pad) { dx = -pad; ++dy; } }
        }
    };

    // prologue: stage + B-load for K-step 0
    stage(0); loadB(0); advance();
    __syncthreads();                         // vmcnt(0): buf0 + bf[0] resident

#pragma unroll 2
    for (int ks = 0; ks < Ksteps; ++ks) {
        const int cur = ks & 1;
        if (ks + 1 < Ksteps) { stage(cur ^ 1); loadB(cur ^ 1); advance(); }  // issue-early
        s16x8 af[4];
#pragma unroll
        for (int i = 0; i < 4; ++i)
            af[i] = *(const s16x8*)&ldsA[cur][(wm * 64 + i * 16 + r16) * 32 + quad * 8];
#pragma unroll
        for (int i = 0; i < 4; ++i)
#pragma unroll
            for (int j = 0; j < 4; ++j)
                acc[i][j] = __builtin_amdgcn_mfma_f32_16x16x32_bf16(af[i], bf[cur][j], acc[i][j], 0, 0, 0);
        __syncthreads();                     // drain stage/loadB(ks+1) + guard buf reuse
    }

#pragma unroll
    for (int j = 0; j < 4; ++j) {
        int col = wn * 64 + j * 16 + r16; int ng = n0 + col;
        float bv = bias[ng];
#pragma unroll
        for (int i = 0; i < 4; ++i) {
            int mb = wm * 64 + i * 16 + quad * 4;
#pragma unroll
            for (int r = 0; r < 4; ++r) {
                int pos2 = blockM * BM + mb + r;
                long oaddr;
                if (TR) {
                    int ow2 = pos2 & Wm1; int t = pos2 >> lw;
                    int oh2 = t & Hm1;    int nb = t >> lh;
                    int oh = 2 * oh2 + py, ow = 2 * ow2 + px;
                    oaddr = ((long)(((nb << (lh + 1)) + oh) << (lw + 1)) + ow) * N + ng;
                } else {
                    oaddr = (long)pos2 * N + ng;
                }
                float v = acc[i][j][r] + bv;
                if (RELU) v = fmaxf(v, 0.f);
                if (OUTF32) {
                    ((float*)outv)[oaddr] = v;
                    if (DUALB) outb[oaddr] = f2bf(v);
                } else {
                    ((bfraw*)outv)[oaddr] = f2bf(v);
                }
            }
        }
    }
}

// ---------------------------------------------------------------------------
// dec2m: convT k3 s1 p1, 64->3ch via MFMA. Block = 16x16 output tile (grid
// 4096), 4 waves. Halo 18x18x64 staged once (px&7 sub-slot swizzle, as R6
// dec2). B = wb2[16][576] staged once, col&7 swizzled. Then 18 ksteps
// (tap, ci-half) x (4 A ds_read_b128 + 1 B read + 4 mfma_16x16x32_bf16)
// per wave, no barriers. A-frag: row r16 -> px (wv*4+i, r16); k = quad*8.
// C: row quad*4+r, col r16 = co. Lanes r16<3 write fp32 NCHW planes + bias.
// ---------------------------------------------------------------------------
__global__ __launch_bounds__(256) void dec2m_kernel(
    const bfraw* __restrict__ in, const bfraw* __restrict__ wb2,
    const float* __restrict__ bias, float* __restrict__ out,
    const bfraw* __restrict__ zp) {
    __shared__ __align__(16) bfraw tile[18 * 18 * 64];   // 41,472 B
    __shared__ __align__(16) bfraw ldsB[16 * 576];       // 18,432 B
    const int tid = threadIdx.x;
    const int b = blockIdx.x;
    const int n = b >> 8, t8 = b & 255;
    const int r0 = (t8 >> 4) * 16, c0 = (t8 & 15) * 16;
    const int wv = tid >> 6, lane = tid & 63;
    const int quad = lane >> 4, r16 = lane & 15;
    const long nbase = (long)n * 65536;

    // ---- stage halo: 2592 segs of 16B (identical to R6 dec2) ----
#pragma unroll
    for (int k = 0; k < 10; ++k) {
        int t = k * 256 + tid;
        int px = t >> 3, d = t & 7;
        int pr = px / 18, pc = px - pr * 18;
        int ih = r0 - 1 + pr, iw = c0 - 1 + pc;
        bool ok = ((unsigned)ih < 256u) & ((unsigned)iw < 256u);
        int s = d ^ (px & 7);                            // pre-swizzled source sub-seg
        const bfraw* g = ok ? in + ((nbase + (long)ih * 256 + iw) << 6) + s * 8 : zp;
        gl_lds16(g, &tile[(k * 256 + wv * 64) * 8]);
    }
    if (tid < 32) {
        int t = 2560 + tid;
        int px = t >> 3, d = t & 7;
        int pr = px / 18, pc = px - pr * 18;
        int ih = r0 - 1 + pr, iw = c0 - 1 + pc;
        bool ok = ((unsigned)ih < 256u) & ((unsigned)iw < 256u);
        int s = d ^ (px & 7);
        const bfraw* g = ok ? in + ((nbase + (long)ih * 256 + iw) << 6) + s * 8 : zp;
        gl_lds16(g, &tile[2560 * 8]);
    }
    // ---- stage B: 1152 segs of 16B; LDS slot (c,s) <- global seg s^(c&7) ----
#pragma unroll
    for (int k = 0; k < 4; ++k) {
        int t = k * 256 + tid;
        int c = t / 72, s = t - c * 72;
        gl_lds16(wb2 + (long)c * 576 + ((s ^ (c & 7)) << 3), &ldsB[(k * 256 + wv * 64) * 8]);
    }
    if (tid < 128) {
        int t = 1024 + tid;
        int c = t / 72, s = t - c * 72;
        gl_lds16(wb2 + (long)c * 576 + ((s ^ (c & 7)) << 3), &ldsB[(1024 + wv * 64) * 8]);
    }
    __syncthreads();   // drains vmcnt: halo + B resident

    f32x4 acc[4];
#pragma unroll
    for (int i = 0; i < 4; ++i) acc[i] = (f32x4)0.f;

    int qb[4];
#pragma unroll
    for (int i = 0; i < 4; ++i) qb[i] = (wv * 4 + i + 1) * 18 + (r16 + 1);

#pragma unroll
    for (int ks = 0; ks < 18; ++ks) {
        const int tap = ks >> 1, h = ks & 1;
        const int dy = tap / 3 - 1, dx = tap % 3 - 1;
        s16x8 bfr = *(const s16x8*)&ldsB[r16 * 576 + (((ks * 4 + quad) ^ (r16 & 7)) << 3)];
        s16x8 afr[4];
#pragma unroll
        for (int i = 0; i < 4; ++i) {
            int q = qb[i] + dy * 18 + dx;
            afr[i] = *(const s16x8*)&tile[(q << 6) + ((((h << 2) + quad) ^ (q & 7)) << 3)];
        }
#pragma unroll
        for (int i = 0; i < 4; ++i)
            acc[i] = __builtin_amdgcn_mfma_f32_16x16x32_bf16(afr[i], bfr, acc[i], 0, 0, 0);
    }

    // ---- epilogue: col r16 = co (0..2 real); row = quad*4 + r ----
    if (r16 < 3) {
        float bv = bias[r16];
        float* plane = out + (((long)(n * 3 + r16)) << 16);
#pragma unroll
        for (int i = 0; i < 4; ++i) {
            int oh = r0 + wv * 4 + i;
#pragma unroll
            for (int r = 0; r < 4; ++r) {
                int ow = c0 + quad * 4 + r;
                plane[((long)oh << 8) + ow] = acc[i][r] + bv;
            }
        }
    }
}

// ---------------------------------------------------------------------------
// VQ partial argmin: grid (512 row-blocks x 4 code-chunks). Block = 128 rows
// x 128 codes, K=256 via 8 ksteps of the R6-proven 2-barrier staged loop
// (18.6 KB LDS -> 4 blocks/CU). dist = ||e||^2 - 2*S; per-lane strict-< in
// ascending code order, 16-lane shuffle reduce, cross-half LDS merge, then
// ONE (val,key) partial per row to pb[chunk*65536 + pos].
// ---------------------------------------------------------------------------
__global__ __launch_bounds__(256) void vqm_kernel(
    const bfraw* __restrict__ zeb, const bfraw* __restrict__ embB,
    const float* __restrict__ esq, float2* __restrict__ pb)
{
    __shared__ __align__(16) bfraw ldsA[128 * 32];
    __shared__ __align__(16) bfraw ldsB[128 * 32];
    __shared__ float sEsq[128];
    __shared__ float sVal[2][128];
    __shared__ int   sKey[2][128];
    const int tid = threadIdx.x, lane = tid & 63, wv = tid >> 6;
    const int wm = wv >> 1, wn = wv & 1;
    const int lrow = lane >> 2, lkof = (lane & 3) * 8;
    const int quad = lane >> 4, r16 = lane & 15;
    const int posBase = blockIdx.x * 128;
    const int codeBase = blockIdx.y * 128;

    if (tid < 128) sEsq[tid] = esq[codeBase + tid];

    const long baseA0 = (long)(posBase + wv * 16 + lrow) * 256 + lkof;
    const long baseA1 = baseA0 + 64 * 256;
    const long baseB0 = (long)(codeBase + wv * 16 + lrow) * 256 + lkof;
    const long baseB1 = baseB0 + 64 * 256;

    f32x4 acc[4][4];
#pragma unroll
    for (int i = 0; i < 4; ++i)
#pragma unroll
        for (int j = 0; j < 4; ++j) acc[i][j] = (f32x4)0.f;

    for (int k = 0; k < 8; ++k) {
        gl_lds16(zeb + baseA0 + k * 32, &ldsA[(wv * 16) * 32]);
        gl_lds16(zeb + baseA1 + k * 32, &ldsA[(64 + wv * 16) * 32]);
        gl_lds16(embB + baseB0 + k * 32, &ldsB[(wv * 16) * 32]);
        gl_lds16(embB + baseB1 + k * 32, &ldsB[(64 + wv * 16) * 32]);
        __syncthreads();
        s16x8 af[4], bf[4];
#pragma unroll
        for (int i = 0; i < 4; ++i)
            af[i] = *(const s16x8*)&ldsA[(wm * 64 + i * 16 + r16) * 32 + quad * 8];
#pragma unroll
        for (int j = 0; j < 4; ++j)
            bf[j] = *(const s16x8*)&ldsB[(wn * 64 + j * 16 + r16) * 32 + quad * 8];
#pragma unroll
        for (int i = 0; i < 4; ++i)
#pragma unroll
            for (int j = 0; j < 4; ++j)
                acc[i][j] = __builtin_amdgcn_mfma_f32_16x16x32_bf16(af[i], bf[j], acc[i][j], 0, 0, 0);
        __syncthreads();
    }

    // epilogue: dist + argmin. C row = i*16 + quad*4 + r (in wm half), col = r16.
#pragma unroll
    for (int i = 0; i < 4; ++i) {
#pragma unroll
        for (int r = 0; r < 4; ++r) {
            float v = 1e30f; int kk = 1 << 30;
#pragma unroll
            for (int j = 0; j < 4; ++j) {           // j ascending -> codes ascending
                int code = codeBase + wn * 64 + j * 16 + r16;
                float d = sEsq[wn * 64 + j * 16 + r16] - 2.f * acc[i][j][r];
                if (d < v) { v = d; kk = code; }    // strict < keeps first index
            }
#pragma unroll
            for (int m = 1; m < 16; m <<= 1) {
                float ov = __shfl_xor(v, m, 64);
                int   ok = __shfl_xor(kk, m, 64);
                if (ov < v || (ov == v && ok < kk)) { v = ov; kk = ok; }
            }
            if (r16 == 0) {
                int localRow = wm * 64 + i * 16 + quad * 4 + r;
                sVal[wn][localRow] = v;
                sKey[wn][localRow] = kk;
            }
        }
    }
    __syncthreads();
    // merge halves: one (val,key) partial per row for this code chunk
    if (tid < 128) {
        float v0 = sVal[0][tid]; int k0 = sKey[0][tid];
        float v1 = sVal[1][tid]; int k1 = sKey[1][tid];
        bool take1 = (v1 < v0) || (v1 == v0 && k1 < k0);
        float2 p; p.x = take1 ? v1 : v0;
        p.y = __int_as_float(take1 ? k1 : k0);
        pb[(long)blockIdx.y * 65536 + posBase + tid] = p;
    }
}

// ---------------------------------------------------------------------------
// VQ merge + gather: 2048 blocks x 32 px. Merge the 4 chunk partials
// (ascending chunk order + key tie-break -> global first-min), one hist
// atomic per px, then stream zq (fp32) + zqb (bf16) at full write BW.
// ---------------------------------------------------------------------------
__global__ __launch_bounds__(256) void vqg_kernel(
    const float2* __restrict__ pb, const float* __restrict__ emb,
    float* __restrict__ zq, bfraw* __restrict__ zqb, int* __restrict__ hist)
{
    __shared__ int sIdxL[32];
    const int tid = threadIdx.x;
    const int posBase = blockIdx.x * 32;
    if (tid < 32) {
        float bv = 1e30f; int bk = 1 << 30;
#pragma unroll
        for (int c = 0; c < 4; ++c) {
            float2 p = pb[(long)c * 65536 + posBase + tid];
            int k = __float_as_int(p.y);
            if (p.x < bv || (p.x == bv && k < bk)) { bv = p.x; bk = k; }
        }
        sIdxL[tid] = bk;
        atomicAdd(&hist[bk], 1);
    }
    __syncthreads();
    const float4* emb4 = (const float4*)emb;
    float4*  zq4  = (float4*)(zq + (long)posBase * 256);
    ushort4* zqb4 = (ushort4*)(zqb + (long)posBase * 256);
#pragma unroll
    for (int it = 0; it < 8; ++it) {
        int i2 = it * 256 + tid;
        int p = i2 >> 6, c = i2 & 63;
        float4 vv = emb4[(long)sIdxL[p] * 64 + c];
        zq4[i2] = vv;
        ushort4 u; u.x = f2bf(vv.x); u.y = f2bf(vv.y); u.z = f2bf(vv.z); u.w = f2bf(vv.w);
        zqb4[i2] = u;
    }
}

// --- perplexity
__global__ void ppl_kernel(const int* __restrict__ hist, float* __restrict__ outp) {
    __shared__ float red[512];
    int t = threadIdx.x;
    float p = (float)hist[t] * (1.0f / 65536.0f);
    red[t] = p * logf(p + 1e-10f);
    __syncthreads();
    for (int s = 256; s; s >>= 1) { if (t < s) red[t] += red[t + s]; __syncthreads(); }
    if (t == 0) *outp = expf(-red[0]);
}

// host: pack convT parity-class tap table (4 entries x 16 bits)
static unsigned long long packFor(int py, int px) {
    unsigned long long pk = 0; int s = 0;
    for (int kh = 0; kh < 4; ++kh) {
        if (((py + 1 - kh) & 1) != 0) continue;
        int dy = (py + 1 - kh) / 2;
        for (int kw = 0; kw < 4; ++kw) {
            if (((px + 1 - kw) & 1) != 0) continue;
            int dx = (px + 1 - kw) / 2;
            unsigned e = ((unsigned)(dy + 1) << 8) | ((unsigned)(dx + 1) << 4) | (unsigned)(kh * 4 + kw);
            pk |= (unsigned long long)e << (16 * s); ++s;
        }
    }
    return pk;
}

extern "C" void kernel_launch(void* const* d_in, const int* in_sizes, int n_in,
                              void* d_out, int out_size, void* d_ws, size_t ws_size,
                              hipStream_t stream) {
    const float* x       = (const float*)d_in[0];
    const float* w_enc1  = (const float*)d_in[1];
    const float* b_enc1  = (const float*)d_in[2];
    const float* w_enc2  = (const float*)d_in[3];
    const float* b_enc2  = (const float*)d_in[4];
    const float* w_prevq = (const float*)d_in[5];
    const float* b_prevq = (const float*)d_in[6];
    const float* emb     = (const float*)d_in[7];
    const float* w_post  = (const float*)d_in[8];
    const float* b_post  = (const float*)d_in[9];
    const float* w_dec1  = (const float*)d_in[10];
    const float* b_dec1  = (const float*)d_in[11];
    const float* w_dec2  = (const float*)d_in[12];
    const float* b_dec2  = (const float*)d_in[13];

    float* out = (float*)d_out;
    float* xr  = out;                     // 3,145,728
    float* ze  = out + 3145728;           // 16,777,216
    float* zq  = ze + 16777216;           // 16,777,216
    float* ppl = zq + 16777216;           // 1

    // ---- workspace carve (bytes) ----
    char* W = (char*)d_ws;
    float* esq  = (float*)(W + 24576);      // 2 KB
    int*   hist = (int*)(W + 28672);        // 2 KB
    bfraw* zp   = (bfraw*)(W + 32768);      // zero page, 256 B
    bfraw* wb2  = (bfraw*)(W + 262144);     // dec2 bf16 [16][576]       18.4 KB
    bfraw* w2b  = (bfraw*)(W + 560128);     // enc2  bf16 [co][16][64]   256 KB
    bfraw* w3b  = (bfraw*)(W + 822272);     // prevq bf16 [co][9][128]   576 KB
    bfraw* wpb  = (bfraw*)(W + 1412096);    // post  bf16 [co][16][256]  1 MB
    bfraw* wd1b = (bfraw*)(W + 2460672);    // dec1  bf16 [co][16][128]  256 KB
    bfraw* wb1  = (bfraw*)(W + 2722816);    // enc1  bf16 [co][64]        8 KB
    bfraw* embB = (bfraw*)(W + 2736128);    // emb   bf16 [512][256]    256 KB
    // bufX (128 MiB @ +4 MiB): sequential lifetimes
    //   a0 [0,33.5M) -> h2 [0,16.8M) -> zeb [16.8M,50.3M) -> zqb [50.3M,83.9M)
    //   -> ddec1 [0,134.2M). pb (2 MB) lives at bufX+0 during VQ (a0/h2 dead).
    char* bufX = W + 4194304;
    bfraw* a0    = (bfraw*)bufX;
    bfraw* h2    = (bfraw*)bufX;
    bfraw* zeb   = (bfraw*)(bufX + 16777216);
    bfraw* zqb   = (bfraw*)(bufX + 50331648);
    bfraw* ddec1 = (bfraw*)bufX;
    float2* pb   = (float2*)bufX;           // 4*65536*8 B = 2 MB (VQ partials)
    // bufY (67.1 MB): dpost
    bfraw* dpost = (bfraw*)(W + 138412032);
    bfraw* h1    = (bfraw*)ze;              // alias: h1 dies before prevq writes z_e

    // ---- weight transforms + precomputes ----
    wb2_kernel<<<36, 256, 0, stream>>>(w_dec2, wb2);
    wb1_kernel<<<16, 256, 0, stream>>>(w_enc1, wb1);
    wtb_kernel<<<512, 256, 0, stream>>>(w_enc2, w2b, 128, 64, 4, 4, 0);
    wtb_kernel<<<1152, 256, 0, stream>>>(w_prevq, w3b, 256, 128, 3, 3, 0);
    wtb_kernel<<<2048, 256, 0, stream>>>(w_post, wpb, 128, 256, 4, 4, 1);
    wtb_kernel<<<512, 256, 0, stream>>>(w_dec1, wd1b, 64, 128, 4, 4, 1);
    wtb_kernel<<<512, 256, 0, stream>>>(emb, embB, 512, 256, 1, 1, 0);
    embsq_kernel<<<512, 64, 0, stream>>>(emb, esq);
    hipMemsetAsync(hist, 0, 512 * sizeof(int), stream);
    hipMemsetAsync(zp, 0, 256, stream);

    // ---- encoder ----
    xpack_kernel<<<1024, 256, 0, stream>>>(x, a0);
    igemm_kernel<256, 64, 4, 1, false, true, false, false><<<dim3(1024, 1, 1), 256, 0, stream>>>(
        a0, wb1, b_enc1, h1, nullptr, zp, 512, 512, 64, 1, 1, 2, 9, 9, 64, 1, 0,
        0ULL, 0ULL, 0ULL, 0ULL);
    igemm_kernel<128, 128, 2, 2, false, true, false, false><<<dim3(512, 1, 1), 256, 0, stream>>>(
        h1, w2b, b_enc2, h2, nullptr, zp, 128, 128, 64, 2, 16, 32, 6, 6, 128, 4, 1,
        0ULL, 0ULL, 0ULL, 0ULL);
    // prevq: dual output ze fp32 + zeb bf16
    igemm_kernel<128, 128, 2, 2, false, false, true, true><<<dim3(512, 2, 1), 256, 0, stream>>>(
        h2, w3b, b_prevq, ze, zeb, zp, 64, 64, 128, 1, 9, 36, 6, 6, 256, 3, 1,
        0ULL, 0ULL, 0ULL, 0ULL);

    // ---- VQ: partial argmin (512x4 blocks) -> merge+gather (2048 blocks) ----
    vqm_kernel<<<dim3(512, 4), 256, 0, stream>>>(zeb, embB, esq, pb);
    vqg_kernel<<<2048, 256, 0, stream>>>(pb, emb, zq, zqb, hist);
    ppl_kernel<<<1, 512, 0, stream>>>(hist, ppl);

    // ---- decoder: 4 parity classes fused via blockIdx.z ----
    igemm_kernel<128, 128, 2, 2, true, false, false, false><<<dim3(512, 1, 4), 256, 0, stream>>>(
        zqb, wpb, b_post, dpost, nullptr, zp, 64, 64, 256, 1, 16, 32, 6, 6, 128, 4, 1,
        packFor(0, 0), packFor(0, 1), packFor(1, 0), packFor(1, 1));
    igemm_kernel<256, 64, 4, 1, true, true, false, false><<<dim3(1024, 1, 4), 256, 0, stream>>>(
        dpost, wd1b, b_dec1, ddec1, nullptr, zp, 128, 128, 128, 1, 16, 16, 7, 7, 64, 4, 1,
        packFor(0, 0), packFor(0, 1), packFor(1, 0), packFor(1, 1));
    dec2m_kernel<<<4096, 256, 0, stream>>>(ddec1, wb2, b_dec2, xr, zp);
}

// Round 9
// 957.031 us; speedup vs baseline: 22.3806x; 22.3806x over previous
//
#include <hip/hip_runtime.h>
#include <stdint.h>

// ---------------------------------------------------------------------------
// VQ-VAE forward on MI355X. Round 13: fix R12's rule-#20 disaster. R12's
// bf[2][4] indexed by runtime lambda arg / loop parity forced dynamic
// register-array indexing -> select-waterfall (VALUBusy 70%, MfmaUtil 0.4%,
// 7.5ms/dispatch). R13: same B->register idea, but two NAMED buffers
// bf0/bf1 passed by reference (compile-time after inlining) and an explicit
// ks+=2 ping-pong loop with literal buffer indices everywhere (Ksteps even
// for all launches: 2/32/36/32/16). LDS stays 16KB (128x128) / 32KB
// (256x64). Numerics bit-identical. Rest unchanged from R11/R12.
// ---------------------------------------------------------------------------

typedef unsigned short bfraw;
typedef __attribute__((ext_vector_type(8))) short s16x8;
typedef __attribute__((ext_vector_type(4))) float f32x4;

__device__ __forceinline__ float bflo(unsigned int u) {
    union { unsigned int i; float f; } v; v.i = u << 16; return v.f;
}
__device__ __forceinline__ float bfhi(unsigned int u) {
    union { unsigned int i; float f; } v; v.i = u & 0xFFFF0000u; return v.f;
}
__device__ __forceinline__ bfraw f2bf(float f) {
    union { float f; unsigned int i; } v; v.f = f;
    unsigned int r = v.i + 0x7FFFu + ((v.i >> 16) & 1u);   // RNE
    return (bfraw)(r >> 16);
}

// async 16B global->LDS. LDS dest: wave-uniform base + lane*16; global src per-lane.
__device__ __forceinline__ void gl_lds16(const void* g, void* l) {
    auto gp = reinterpret_cast<const __attribute__((address_space(1))) unsigned int*>(
        reinterpret_cast<uintptr_t>(g));
    auto lp = reinterpret_cast<__attribute__((address_space(3))) unsigned int*>(
        reinterpret_cast<uintptr_t>(l));
    __builtin_amdgcn_global_load_lds(gp, lp, 16, 0, 0);
}

// --- weight transform (bf16, [co][tap][ci]) for MFMA convs (B as [n][k]);
//     with KH=KW=1 also converts emb[512][256] to bf16 B layout.
__global__ void wtb_kernel(const float* __restrict__ w, bfraw* __restrict__ wt,
                           int Cout, int Cin, int KH, int KW, int transposed) {
    int n = Cout * Cin * KH * KW;
    int NT = KH * KW;
    for (int i = blockIdx.x * blockDim.x + threadIdx.x; i < n; i += gridDim.x * blockDim.x) {
        int ci = i % Cin; int t = i / Cin;
        int tap = t % NT; int co = t / NT;
        int kh = tap / KW, kw = tap % KW;
        float v = transposed ? w[(((long)ci * Cout + co) * KH + kh) * KW + kw]
                             : w[(((long)co * Cin + ci) * KH + kh) * KW + kw];
        wt[i] = f2bf(v);
    }
}

// --- dec2 weight pack: wb2[16][576] bf16, B[co][tap*64+ci]; rows 3..15 zero.
//     convT k3 p1 == conv with wf[co][ci][kh'][kw'] = w[ci][co][2-kh'][2-kw'].
__global__ void wb2_kernel(const float* __restrict__ w, bfraw* __restrict__ wt) {
    int i = blockIdx.x * 256 + threadIdx.x;   // 9216 = 16*576
    if (i >= 9216) return;
    int ci = i & 63; int t = i >> 6;          // t = co*9 + tap
    int tap = t % 9, co = t / 9;
    bfraw v = 0;
    if (co < 3) {
        int kh = 2 - tap / 3, kw = 2 - tap % 3;
        v = f2bf(w[(((long)ci * 3 + co) * 3 + kh) * 3 + kw]);
    }
    wt[(long)co * 576 + tap * 64 + ci] = v;
}

// --- enc1 weight pack: wb1[co][k64], k=(kh*4+kw)*3+ci (48 real, 16 zero)
__global__ void wb1_kernel(const float* __restrict__ w, bfraw* __restrict__ wt) {
    int i = blockIdx.x * 256 + threadIdx.x;
    if (i >= 4096) return;
    int k = i & 63, co = i >> 6;
    bfraw v = 0;
    if (k < 48) {
        int ci = k % 3, tap = k / 3, kh = tap >> 2, kw = tap & 3;
        v = f2bf(w[(((long)co * 3 + ci) * 4 + kh) * 4 + kw]);
    }
    wt[(long)co * 64 + k] = v;
}

// --- enc1 im2col: x NCHW fp32 -> A0[pos][64] bf16 (48 patch vals + 16 zeros)
__global__ __launch_bounds__(256) void xpack_kernel(const float* __restrict__ x,
                                                    bfraw* __restrict__ a0) {
    int pos = blockIdx.x * 256 + threadIdx.x;        // 262144
    int ow = pos & 127, oh = (pos >> 7) & 127, n = pos >> 14;
    __align__(16) bfraw v[64];
#pragma unroll
    for (int i = 0; i < 64; ++i) v[i] = 0;
#pragma unroll
    for (int kh = 0; kh < 4; ++kh) {
        int ih = 2 * oh - 1 + kh; if ((unsigned)ih >= 256u) continue;
#pragma unroll
        for (int kw = 0; kw < 4; ++kw) {
            int iw = 2 * ow - 1 + kw; if ((unsigned)iw >= 256u) continue;
#pragma unroll
            for (int ci = 0; ci < 3; ++ci)
                v[(kh * 4 + kw) * 3 + ci] =
                    f2bf(x[(((long)n * 3 + ci) * 256 + ih) * 256 + iw]);
        }
    }
    uint4* dst = (uint4*)(a0 + (long)pos * 64);
    const uint4* src = (const uint4*)v;
#pragma unroll
    for (int i = 0; i < 8; ++i) dst[i] = src[i];
}

// --- emb row norms
__global__ void embsq_kernel(const float* __restrict__ emb, float* __restrict__ esq) {
    int k = blockIdx.x, lane = threadIdx.x;
    float s = 0.f;
    for (int d = lane; d < 256; d += 64) { float v = emb[k * 256 + d]; s += v * v; }
    for (int o = 32; o; o >>= 1) s += __shfl_down(s, o, 64);
    if (lane == 0) esq[k] = s;
}

// ---------------------------------------------------------------------------
// MFMA implicit GEMM. C[MxN] = A[MxK]*B[KxN]. A: 2-phase LDS double-buffer.
// B: direct global register loads (L2-resident panels) into NAMED buffers
// bf0/bf1 (by-reference loads, compile-time indices only — rule #20).
// Explicit ks+=2 ping-pong (Ksteps even). blockIdx.z = convT parity class;
// XCD-bijective blockM swizzle.
// ---------------------------------------------------------------------------
template<int BM, int BN, int WM, int WN, bool TR, bool RELU, bool OUTF32, bool DUALB>
__global__ __launch_bounds__(256) void igemm_kernel(
    const bfraw* __restrict__ in, const bfraw* __restrict__ wt,
    const float* __restrict__ bias, void* __restrict__ outv,
    bfraw* __restrict__ outb, const bfraw* __restrict__ zp,
    int Hin, int Win, int Cin, int sf, int NTW, int Ksteps,
    int lw, int lh, int N, int KW, int pad,
    unsigned long long pk0, unsigned long long pk1,
    unsigned long long pk2, unsigned long long pk3)
{
    constexpr int APASS = BM / 64;
    __shared__ __align__(16) bfraw ldsA0[BM * 32];
    __shared__ __align__(16) bfraw ldsA1[BM * 32];
    const int tid = threadIdx.x, lane = tid & 63, wv = tid >> 6;
    const int wm = wv / WN, wn = wv % WN;
    const int lrow = lane >> 2, lkof = (lane & 3) * 8;
    const int n0 = blockIdx.y * BN;
    const int Wm1 = (1 << lw) - 1, Hm1 = (1 << lh) - 1;
    // XCD-bijective swizzle (gridDim.x % 8 == 0 for all launches)
    const int bid = blockIdx.x;
    const int blockM = (bid & 7) * ((int)gridDim.x >> 3) + (bid >> 3);
    // convT parity class
    const int cls = blockIdx.z;
    const unsigned long long pack = (cls == 0) ? pk0 : (cls == 1) ? pk1
                                  : (cls == 2) ? pk2 : pk3;
    const int py = cls >> 1, px = cls & 1;

    const int quad = lane >> 4, r16 = lane & 15;

    long baseA[APASS]; int ihb[APASS], iwb[APASS];
#pragma unroll
    for (int p = 0; p < APASS; ++p) {
        int m = p * 64 + wv * 16 + lrow;
        int pos = blockM * BM + m;
        int ow = pos & Wm1; int t = pos >> lw;
        int oh = t & Hm1;   int nb = t >> lh;
        ihb[p] = oh * sf; iwb[p] = ow * sf;
        baseA[p] = ((long)(nb * Hin + ihb[p]) * Win + iwb[p]) * (long)Cin + lkof;
    }
    // per-lane B row bases (col = wn*64 + j*16 + r16), k-offset added per kstep
    long baseB[4];
#pragma unroll
    for (int j = 0; j < 4; ++j)
        baseB[j] = (long)(n0 + wn * 64 + j * 16 + r16) * ((long)NTW * Cin) + quad * 8;

    f32x4 acc[4][4];
#pragma unroll
    for (int i = 0; i < 4; ++i)
#pragma unroll
        for (int j = 0; j < 4; ++j) acc[i][j] = (f32x4)0.f;

    int ci0 = 0, tslot = 0, dy, dx, wk;
    if (TR) {
        unsigned e = (unsigned)pack & 0xFFFFu;
        dy = (int)((e >> 8) & 3) - 1; dx = (int)((e >> 4) & 3) - 1; wk = (int)(e & 15u);
    } else { dy = -pad; dx = -pad; wk = 0; }

    s16x8 bf0[4], bf1[4];

    // ---- helpers: every index compile-time after inlining ----
    auto stage = [&](bfraw* dstA) {
        long offA = ((long)(dy * Win + dx)) * Cin + ci0;
#pragma unroll
        for (int p = 0; p < APASS; ++p) {
            int ih = ihb[p] + dy, iw = iwb[p] + dx;
            bool ok = ((unsigned)ih < (unsigned)Hin) & ((unsigned)iw < (unsigned)Win);
            const bfraw* g = ok ? (in + baseA[p] + offA) : (zp + lkof);
            gl_lds16(g, dstA + (p * 64 + wv * 16) * 32);
        }
    };
    auto loadB = [&](s16x8 (&dst)[4]) {
        long offB = (long)wk * Cin + ci0;
#pragma unroll
        for (int j = 0; j < 4; ++j)
            dst[j] = *(const s16x8*)(wt + baseB[j] + offB);
    };
    auto advance = [&]() {
        ci0 += 32;
        if (ci0 == Cin) {
            ci0 = 0; ++tslot;
            if (TR) {
                unsigned e = (unsigned)(pack >> ((tslot & 3) * 16)) & 0xFFFFu;
                dy = (int)((e >> 8) & 3) - 1; dx = (int)((e >> 4) & 3) - 1; wk = (int)(e & 15u);
            } else { ++wk; ++dx; if (dx == KW - pad) { dx = -pad; ++dy; } }
        }
    };
    auto compute = [&](const bfraw* A, const s16x8 (&bfr)[4]) {
        s16x8 af[4];
#pragma unroll
        for (int i = 0; i < 4; ++i)
            af[i] = *(const s16x8*)(A + (wm * 64 + i * 16 + r16) * 32 + quad * 8);
#pragma unroll
        for (int i = 0; i < 4; ++i)
#pragma unroll
            for (int j = 0; j < 4; ++j)
                acc[i][j] = __builtin_amdgcn_mfma_f32_16x16x32_bf16(af[i], bfr[j], acc[i][j], 0, 0, 0);
    };

    // prologue: K-step 0 into buf0/bf0
    stage(ldsA0); loadB(bf0); advance();
    __syncthreads();                         // vmcnt(0): ldsA0 resident

    for (int ks = 0; ks < Ksteps; ks += 2) { // Ksteps even for all launches
        // step ks: compute(buf0, bf0); prefetch step ks+1 into buf1/bf1
        stage(ldsA1); loadB(bf1); advance();
        compute(ldsA0, bf0);
        __syncthreads();
        // step ks+1: compute(buf1, bf1); prefetch ks+2 into buf0/bf0
        if (ks + 2 < Ksteps) { stage(ldsA0); loadB(bf0); advance(); }
        compute(ldsA1, bf1);
        __syncthreads();
    }

#pragma unroll
    for (int j = 0; j < 4; ++j) {
        int col = wn * 64 + j * 16 + r16; int ng = n0 + col;
        float bv = bias[ng];
#pragma unroll
        for (int i = 0; i < 4; ++i) {
            int mb = wm * 64 + i * 16 + quad * 4;
#pragma unroll
            for (int r = 0; r < 4; ++r) {
                int pos2 = blockM * BM + mb + r;
                long oaddr;
                if (TR) {
                    int ow2 = pos2 & Wm1; int t = pos2 >> lw;
                    int oh2 = t & Hm1;    int nb = t >> lh;
                    int oh = 2 * oh2 + py, ow = 2 * ow2 + px;
                    oaddr = ((long)(((nb << (lh + 1)) + oh) << (lw + 1)) + ow) * N + ng;
                } else {
                    oaddr = (long)pos2 * N + ng;
                }
                float v = acc[i][j][r] + bv;
                if (RELU) v = fmaxf(v, 0.f);
                if (OUTF32) {
                    ((float*)outv)[oaddr] = v;
                    if (DUALB) outb[oaddr] = f2bf(v);
                } else {
                    ((bfraw*)outv)[oaddr] = f2bf(v);
                }
            }
        }
    }
}

// ---------------------------------------------------------------------------
// dec2m: convT k3 s1 p1, 64->3ch via MFMA. Block = 16x16 output tile (grid
// 4096), 4 waves. Halo 18x18x64 staged once (px&7 sub-slot swizzle, as R6
// dec2). B = wb2[16][576] staged once, col&7 swizzled. Then 18 ksteps
// (tap, ci-half) x (4 A ds_read_b128 + 1 B read + 4 mfma_16x16x32_bf16)
// per wave, no barriers. A-frag: row r16 -> px (wv*4+i, r16); k = quad*8.
// C: row quad*4+r, col r16 = co. Lanes r16<3 write fp32 NCHW planes + bias.
// ---------------------------------------------------------------------------
__global__ __launch_bounds__(256) void dec2m_kernel(
    const bfraw* __restrict__ in, const bfraw* __restrict__ wb2,
    const float* __restrict__ bias, float* __restrict__ out,
    const bfraw* __restrict__ zp) {
    __shared__ __align__(16) bfraw tile[18 * 18 * 64];   // 41,472 B
    __shared__ __align__(16) bfraw ldsB[16 * 576];       // 18,432 B
    const int tid = threadIdx.x;
    const int b = blockIdx.x;
    const int n = b >> 8, t8 = b & 255;
    const int r0 = (t8 >> 4) * 16, c0 = (t8 & 15) * 16;
    const int wv = tid >> 6, lane = tid & 63;
    const int quad = lane >> 4, r16 = lane & 15;
    const long nbase = (long)n * 65536;

    // ---- stage halo: 2592 segs of 16B (identical to R6 dec2) ----
#pragma unroll
    for (int k = 0; k < 10; ++k) {
        int t = k * 256 + tid;
        int px = t >> 3, d = t & 7;
        int pr = px / 18, pc = px - pr * 18;
        int ih = r0 - 1 + pr, iw = c0 - 1 + pc;
        bool ok = ((unsigned)ih < 256u) & ((unsigned)iw < 256u);
        int s = d ^ (px & 7);                            // pre-swizzled source sub-seg
        const bfraw* g = ok ? in + ((nbase + (long)ih * 256 + iw) << 6) + s * 8 : zp;
        gl_lds16(g, &tile[(k * 256 + wv * 64) * 8]);
    }
    if (tid < 32) {
        int t = 2560 + tid;
        int px = t >> 3, d = t & 7;
        int pr = px / 18, pc = px - pr * 18;
        int ih = r0 - 1 + pr, iw = c0 - 1 + pc;
        bool ok = ((unsigned)ih < 256u) & ((unsigned)iw < 256u);
        int s = d ^ (px & 7);
        const bfraw* g = ok ? in + ((nbase + (long)ih * 256 + iw) << 6) + s * 8 : zp;
        gl_lds16(g, &tile[2560 * 8]);
    }
    // ---- stage B: 1152 segs of 16B; LDS slot (c,s) <- global seg s^(c&7) ----
#pragma unroll
    for (int k = 0; k < 4; ++k) {
        int t = k * 256 + tid;
        int c = t / 72, s = t - c * 72;
        gl_lds16(wb2 + (long)c * 576 + ((s ^ (c & 7)) << 3), &ldsB[(k * 256 + wv * 64) * 8]);
    }
    if (tid < 128) {
        int t = 1024 + tid;
        int c = t / 72, s = t - c * 72;
        gl_lds16(wb2 + (long)c * 576 + ((s ^ (c & 7)) << 3), &ldsB[(1024 + wv * 64) * 8]);
    }
    __syncthreads();   // drains vmcnt: halo + B resident

    f32x4 acc[4];
#pragma unroll
    for (int i = 0; i < 4; ++i) acc[i] = (f32x4)0.f;

    int qb[4];
#pragma unroll
    for (int i = 0; i < 4; ++i) qb[i] = (wv * 4 + i + 1) * 18 + (r16 + 1);

#pragma unroll
    for (int ks = 0; ks < 18; ++ks) {
        const int tap = ks >> 1, h = ks & 1;
        const int dy = tap / 3 - 1, dx = tap % 3 - 1;
        s16x8 bfr = *(const s16x8*)&ldsB[r16 * 576 + (((ks * 4 + quad) ^ (r16 & 7)) << 3)];
        s16x8 afr[4];
#pragma unroll
        for (int i = 0; i < 4; ++i) {
            int q = qb[i] + dy * 18 + dx;
            afr[i] = *(const s16x8*)&tile[(q << 6) + ((((h << 2) + quad) ^ (q & 7)) << 3)];
        }
#pragma unroll
        for (int i = 0; i < 4; ++i)
            acc[i] = __builtin_amdgcn_mfma_f32_16x16x32_bf16(afr[i], bfr, acc[i], 0, 0, 0);
    }

    // ---- epilogue: col r16 = co (0..2 real); row = quad*4 + r ----
    if (r16 < 3) {
        float bv = bias[r16];
        float* plane = out + (((long)(n * 3 + r16)) << 16);
#pragma unroll
        for (int i = 0; i < 4; ++i) {
            int oh = r0 + wv * 4 + i;
#pragma unroll
            for (int r = 0; r < 4; ++r) {
                int ow = c0 + quad * 4 + r;
                plane[((long)oh << 8) + ow] = acc[i][r] + bv;
            }
        }
    }
}

// ---------------------------------------------------------------------------
// VQ partial argmin: grid (512 row-blocks x 4 code-chunks). Block = 128 rows
// x 128 codes, K=256 via 8 ksteps of the R6-proven 2-barrier staged loop
// (18.6 KB LDS -> 4 blocks/CU). dist = ||e||^2 - 2*S; per-lane strict-< in
// ascending code order, 16-lane shuffle reduce, cross-half LDS merge, then
// ONE (val,key) partial per row to pb[chunk*65536 + pos].
// ---------------------------------------------------------------------------
__global__ __launch_bounds__(256) void vqm_kernel(
    const bfraw* __restrict__ zeb, const bfraw* __restrict__ embB,
    const float* __restrict__ esq, float2* __restrict__ pb)
{
    __shared__ __align__(16) bfraw ldsA[128 * 32];
    __shared__ __align__(16) bfraw ldsB[128 * 32];
    __shared__ float sEsq[128];
    __shared__ float sVal[2][128];
    __shared__ int   sKey[2][128];
    const int tid = threadIdx.x, lane = tid & 63, wv = tid >> 6;
    const int wm = wv >> 1, wn = wv & 1;
    const int lrow = lane >> 2, lkof = (lane & 3) * 8;
    const int quad = lane >> 4, r16 = lane & 15;
    const int posBase = blockIdx.x * 128;
    const int codeBase = blockIdx.y * 128;

    if (tid < 128) sEsq[tid] = esq[codeBase + tid];

    const long baseA0 = (long)(posBase + wv * 16 + lrow) * 256 + lkof;
    const long baseA1 = baseA0 + 64 * 256;
    const long baseB0 = (long)(codeBase + wv * 16 + lrow) * 256 + lkof;
    const long baseB1 = baseB0 + 64 * 256;

    f32x4 acc[4][4];
#pragma unroll
    for (int i = 0; i < 4; ++i)
#pragma unroll
        for (int j = 0; j < 4; ++j) acc[i][j] = (f32x4)0.f;

    for (int k = 0; k < 8; ++k) {
        gl_lds16(zeb + baseA0 + k * 32, &ldsA[(wv * 16) * 32]);
        gl_lds16(zeb + baseA1 + k * 32, &ldsA[(64 + wv * 16) * 32]);
        gl_lds16(embB + baseB0 + k * 32, &ldsB[(wv * 16) * 32]);
        gl_lds16(embB + baseB1 + k * 32, &ldsB[(64 + wv * 16) * 32]);
        __syncthreads();
        s16x8 af[4], bf[4];
#pragma unroll
        for (int i = 0; i < 4; ++i)
            af[i] = *(const s16x8*)&ldsA[(wm * 64 + i * 16 + r16) * 32 + quad * 8];
#pragma unroll
        for (int j = 0; j < 4; ++j)
            bf[j] = *(const s16x8*)&ldsB[(wn * 64 + j * 16 + r16) * 32 + quad * 8];
#pragma unroll
        for (int i = 0; i < 4; ++i)
#pragma unroll
            for (int j = 0; j < 4; ++j)
                acc[i][j] = __builtin_amdgcn_mfma_f32_16x16x32_bf16(af[i], bf[j], acc[i][j], 0, 0, 0);
        __syncthreads();
    }

    // epilogue: dist + argmin. C row = i*16 + quad*4 + r (in wm half), col = r16.
#pragma unroll
    for (int i = 0; i < 4; ++i) {
#pragma unroll
        for (int r = 0; r < 4; ++r) {
            float v = 1e30f; int kk = 1 << 30;
#pragma unroll
            for (int j = 0; j < 4; ++j) {           // j ascending -> codes ascending
                int code = codeBase + wn * 64 + j * 16 + r16;
                float d = sEsq[wn * 64 + j * 16 + r16] - 2.f * acc[i][j][r];
                if (d < v) { v = d; kk = code; }    // strict < keeps first index
            }
#pragma unroll
            for (int m = 1; m < 16; m <<= 1) {
                float ov = __shfl_xor(v, m, 64);
                int   ok = __shfl_xor(kk, m, 64);
                if (ov < v || (ov == v && ok < kk)) { v = ov; kk = ok; }
            }
            if (r16 == 0) {
                int localRow = wm * 64 + i * 16 + quad * 4 + r;
                sVal[wn][localRow] = v;
                sKey[wn][localRow] = kk;
            }
        }
    }
    __syncthreads();
    // merge halves: one (val,key) partial per row for this code chunk
    if (tid < 128) {
        float v0 = sVal[0][tid]; int k0 = sKey[0][tid];
        float v1 = sVal[1][tid]; int k1 = sKey[1][tid];
        bool take1 = (v1 < v0) || (v1 == v0 && k1 < k0);
        float2 p; p.x = take1 ? v1 : v0;
        p.y = __int_as_float(take1 ? k1 : k0);
        pb[(long)blockIdx.y * 65536 + posBase + tid] = p;
    }
}

// ---------------------------------------------------------------------------
// VQ merge + gather: 2048 blocks x 32 px. Merge the 4 chunk partials
// (ascending chunk order + key tie-break -> global first-min), one hist
// atomic per px, then stream zq (fp32) + zqb (bf16) at full write BW.
// ---------------------------------------------------------------------------
__global__ __launch_bounds__(256) void vqg_kernel(
    const float2* __restrict__ pb, const float* __restrict__ emb,
    float* __restrict__ zq, bfraw* __restrict__ zqb, int* __restrict__ hist)
{
    __shared__ int sIdxL[32];
    const int tid = threadIdx.x;
    const int posBase = blockIdx.x * 32;
    if (tid < 32) {
        float bv = 1e30f; int bk = 1 << 30;
#pragma unroll
        for (int c = 0; c < 4; ++c) {
            float2 p = pb[(long)c * 65536 + posBase + tid];
            int k = __float_as_int(p.y);
            if (p.x < bv || (p.x == bv && k < bk)) { bv = p.x; bk = k; }
        }
        sIdxL[tid] = bk;
        atomicAdd(&hist[bk], 1);
    }
    __syncthreads();
    const float4* emb4 = (const float4*)emb;
    float4*  zq4  = (float4*)(zq + (long)posBase * 256);
    ushort4* zqb4 = (ushort4*)(zqb + (long)posBase * 256);
#pragma unroll
    for (int it = 0; it < 8; ++it) {
        int i2 = it * 256 + tid;
        int p = i2 >> 6, c = i2 & 63;
        float4 vv = emb4[(long)sIdxL[p] * 64 + c];
        zq4[i2] = vv;
        ushort4 u; u.x = f2bf(vv.x); u.y = f2bf(vv.y); u.z = f2bf(vv.z); u.w = f2bf(vv.w);
        zqb4[i2] = u;
    }
}

// --- perplexity
__global__ void ppl_kernel(const int* __restrict__ hist, float* __restrict__ outp) {
    __shared__ float red[512];
    int t = threadIdx.x;
    float p = (float)hist[t] * (1.0f / 65536.0f);
    red[t] = p * logf(p + 1e-10f);
    __syncthreads();
    for (int s = 256; s; s >>= 1) { if (t < s) red[t] += red[t + s]; __syncthreads(); }
    if (t == 0) *outp = expf(-red[0]);
}

// host: pack convT parity-class tap table (4 entries x 16 bits)
static unsigned long long packFor(int py, int px) {
    unsigned long long pk = 0; int s = 0;
    for (int kh = 0; kh < 4; ++kh) {
        if (((py + 1 - kh) & 1) != 0) continue;
        int dy = (py + 1 - kh) / 2;
        for (int kw = 0; kw < 4; ++kw) {
            if (((px + 1 - kw) & 1) != 0) continue;
            int dx = (px + 1 - kw) / 2;
            unsigned e = ((unsigned)(dy + 1) << 8) | ((unsigned)(dx + 1) << 4) | (unsigned)(kh * 4 + kw);
            pk |= (unsigned long long)e << (16 * s); ++s;
        }
    }
    return pk;
}

extern "C" void kernel_launch(void* const* d_in, const int* in_sizes, int n_in,
                              void* d_out, int out_size, void* d_ws, size_t ws_size,
                              hipStream_t stream) {
    const float* x       = (const float*)d_in[0];
    const float* w_enc1  = (const float*)d_in[1];
    const float* b_enc1  = (const float*)d_in[2];
    const float* w_enc2  = (const float*)d_in[3];
    const float* b_enc2  = (const float*)d_in[4];
    const float* w_prevq = (const float*)d_in[5];
    const float* b_prevq = (const float*)d_in[6];
    const float* emb     = (const float*)d_in[7];
    const float* w_post  = (const float*)d_in[8];
    const float* b_post  = (const float*)d_in[9];
    const float* w_dec1  = (const float*)d_in[10];
    const float* b_dec1  = (const float*)d_in[11];
    const float* w_dec2  = (const float*)d_in[12];
    const float* b_dec2  = (const float*)d_in[13];

    float* out = (float*)d_out;
    float* xr  = out;                     // 3,145,728
    float* ze  = out + 3145728;           // 16,777,216
    float* zq  = ze + 16777216;           // 16,777,216
    float* ppl = zq + 16777216;           // 1

    // ---- workspace carve (bytes) ----
    char* W = (char*)d_ws;
    float* esq  = (float*)(W + 24576);      // 2 KB
    int*   hist = (int*)(W + 28672);        // 2 KB
    bfraw* zp   = (bfraw*)(W + 32768);      // zero page, 256 B
    bfraw* wb2  = (bfraw*)(W + 262144);     // dec2 bf16 [16][576]       18.4 KB
    bfraw* w2b  = (bfraw*)(W + 560128);     // enc2  bf16 [co][16][64]   256 KB
    bfraw* w3b  = (bfraw*)(W + 822272);     // prevq bf16 [co][9][128]   576 KB
    bfraw* wpb  = (bfraw*)(W + 1412096);    // post  bf16 [co][16][256]  1 MB
    bfraw* wd1b = (bfraw*)(W + 2460672);    // dec1  bf16 [co][16][128]  256 KB
    bfraw* wb1  = (bfraw*)(W + 2722816);    // enc1  bf16 [co][64]        8 KB
    bfraw* embB = (bfraw*)(W + 2736128);    // emb   bf16 [512][256]    256 KB
    // bufX (128 MiB @ +4 MiB): sequential lifetimes
    //   a0 [0,33.5M) -> h2 [0,16.8M) -> zeb [16.8M,50.3M) -> zqb [50.3M,83.9M)
    //   -> ddec1 [0,134.2M). pb (2 MB) lives at bufX+0 during VQ (a0/h2 dead).
    char* bufX = W + 4194304;
    bfraw* a0    = (bfraw*)bufX;
    bfraw* h2    = (bfraw*)bufX;
    bfraw* zeb   = (bfraw*)(bufX + 16777216);
    bfraw* zqb   = (bfraw*)(bufX + 50331648);
    bfraw* ddec1 = (bfraw*)bufX;
    float2* pb   = (float2*)bufX;           // 4*65536*8 B = 2 MB (VQ partials)
    // bufY (67.1 MB): dpost
    bfraw* dpost = (bfraw*)(W + 138412032);
    bfraw* h1    = (bfraw*)ze;              // alias: h1 dies before prevq writes z_e

    // ---- weight transforms + precomputes ----
    wb2_kernel<<<36, 256, 0, stream>>>(w_dec2, wb2);
    wb1_kernel<<<16, 256, 0, stream>>>(w_enc1, wb1);
    wtb_kernel<<<512, 256, 0, stream>>>(w_enc2, w2b, 128, 64, 4, 4, 0);
    wtb_kernel<<<1152, 256, 0, stream>>>(w_prevq, w3b, 256, 128, 3, 3, 0);
    wtb_kernel<<<2048, 256, 0, stream>>>(w_post, wpb, 128, 256, 4, 4, 1);
    wtb_kernel<<<512, 256, 0, stream>>>(w_dec1, wd1b, 64, 128, 4, 4, 1);
    wtb_kernel<<<512, 256, 0, stream>>>(emb, embB, 512, 256, 1, 1, 0);
    embsq_kernel<<<512, 64, 0, stream>>>(emb, esq);
    hipMemsetAsync(hist, 0, 512 * sizeof(int), stream);
    hipMemsetAsync(zp, 0, 256, stream);

    // ---- encoder ----
    xpack_kernel<<<1024, 256, 0, stream>>>(x, a0);
    igemm_kernel<256, 64, 4, 1, false, true, false, false><<<dim3(1024, 1, 1), 256, 0, stream>>>(
        a0, wb1, b_enc1, h1, nullptr, zp, 512, 512, 64, 1, 1, 2, 9, 9, 64, 1, 0,
        0ULL, 0ULL, 0ULL, 0ULL);
    igemm_kernel<128, 128, 2, 2, false, true, false, false><<<dim3(512, 1, 1), 256, 0, stream>>>(
        h1, w2b, b_enc2, h2, nullptr, zp, 128, 128, 64, 2, 16, 32, 6, 6, 128, 4, 1,
        0ULL, 0ULL, 0ULL, 0ULL);
    // prevq: dual output ze fp32 + zeb bf16
    igemm_kernel<128, 128, 2, 2, false, false, true, true><<<dim3(512, 2, 1), 256, 0, stream>>>(
        h2, w3b, b_prevq, ze, zeb, zp, 64, 64, 128, 1, 9, 36, 6, 6, 256, 3, 1,
        0ULL, 0ULL, 0ULL, 0ULL);

    // ---- VQ: partial argmin (512x4 blocks) -> merge+gather (2048 blocks) ----
    vqm_kernel<<<dim3(512, 4), 256, 0, stream>>>(zeb, embB, esq, pb);
    vqg_kernel<<<2048, 256, 0, stream>>>(pb, emb, zq, zqb, hist);
    ppl_kernel<<<1, 512, 0, stream>>>(hist, ppl);

    // ---- decoder: 4 parity classes fused via blockIdx.z ----
    igemm_kernel<128, 128, 2, 2, true, false, false, false><<<dim3(512, 1, 4), 256, 0, stream>>>(
        zqb, wpb, b_post, dpost, nullptr, zp, 64, 64, 256, 1, 16, 32, 6, 6, 128, 4, 1,
        packFor(0, 0), packFor(0, 1), packFor(1, 0), packFor(1, 1));
    igemm_kernel<256, 64, 4, 1, true, true, false, false><<<dim3(1024, 1, 4), 256, 0, stream>>>(
        dpost, wd1b, b_dec1, ddec1, nullptr, zp, 128, 128, 128, 1, 16, 16, 7, 7, 64, 4, 1,
        packFor(0, 0), packFor(0, 1), packFor(1, 0), packFor(1, 1));
    dec2m_kernel<<<4096, 256, 0, stream>>>(ddec1, wb2, b_dec2, xr, zp);
}

// Round 10
// 701.722 us; speedup vs baseline: 30.5234x; 1.3638x over previous
//
#include <hip/hip_runtime.h>
#include <stdint.h>

// ---------------------------------------------------------------------------
// VQ-VAE forward on MI355X. Round 14: revert igemm to R11 structure (LDS-
// staged B, 2-phase dbuf — R13's B-register loads lost L2 residency under
// A-streaming: FETCH 500->630MB, BW 4.0->3.25TB/s, dec1 173->244us) + NEW
// class-coalescing XCD grid mapping for the convT dispatches: 1D grid,
// xcd = bid&7 owns a contiguous tile range with the tile's 4 parity classes
// back-to-back (cls=(bid>>3)&3, blockM=(bid&7)*(nwg/32)+(bid>>5)). The 4
// class-blocks sharing an A-tile run adjacently on ONE XCD -> A fetched to
// that L2 once, reused 4x (FETCH ~/2). Numerics bit-identical.
// ---------------------------------------------------------------------------

typedef unsigned short bfraw;
typedef __attribute__((ext_vector_type(8))) short s16x8;
typedef __attribute__((ext_vector_type(4))) float f32x4;

__device__ __forceinline__ float bflo(unsigned int u) {
    union { unsigned int i; float f; } v; v.i = u << 16; return v.f;
}
__device__ __forceinline__ float bfhi(unsigned int u) {
    union { unsigned int i; float f; } v; v.i = u & 0xFFFF0000u; return v.f;
}
__device__ __forceinline__ bfraw f2bf(float f) {
    union { float f; unsigned int i; } v; v.f = f;
    unsigned int r = v.i + 0x7FFFu + ((v.i >> 16) & 1u);   // RNE
    return (bfraw)(r >> 16);
}

// async 16B global->LDS. LDS dest: wave-uniform base + lane*16; global src per-lane.
__device__ __forceinline__ void gl_lds16(const void* g, void* l) {
    auto gp = reinterpret_cast<const __attribute__((address_space(1))) unsigned int*>(
        reinterpret_cast<uintptr_t>(g));
    auto lp = reinterpret_cast<__attribute__((address_space(3))) unsigned int*>(
        reinterpret_cast<uintptr_t>(l));
    __builtin_amdgcn_global_load_lds(gp, lp, 16, 0, 0);
}

// --- weight transform (bf16, [co][tap][ci]) for MFMA convs (B as [n][k]);
//     with KH=KW=1 also converts emb[512][256] to bf16 B layout.
__global__ void wtb_kernel(const float* __restrict__ w, bfraw* __restrict__ wt,
                           int Cout, int Cin, int KH, int KW, int transposed) {
    int n = Cout * Cin * KH * KW;
    int NT = KH * KW;
    for (int i = blockIdx.x * blockDim.x + threadIdx.x; i < n; i += gridDim.x * blockDim.x) {
        int ci = i % Cin; int t = i / Cin;
        int tap = t % NT; int co = t / NT;
        int kh = tap / KW, kw = tap % KW;
        float v = transposed ? w[(((long)ci * Cout + co) * KH + kh) * KW + kw]
                             : w[(((long)co * Cin + ci) * KH + kh) * KW + kw];
        wt[i] = f2bf(v);
    }
}

// --- dec2 weight pack: wb2[16][576] bf16, B[co][tap*64+ci]; rows 3..15 zero.
//     convT k3 p1 == conv with wf[co][ci][kh'][kw'] = w[ci][co][2-kh'][2-kw'].
__global__ void wb2_kernel(const float* __restrict__ w, bfraw* __restrict__ wt) {
    int i = blockIdx.x * 256 + threadIdx.x;   // 9216 = 16*576
    if (i >= 9216) return;
    int ci = i & 63; int t = i >> 6;          // t = co*9 + tap
    int tap = t % 9, co = t / 9;
    bfraw v = 0;
    if (co < 3) {
        int kh = 2 - tap / 3, kw = 2 - tap % 3;
        v = f2bf(w[(((long)ci * 3 + co) * 3 + kh) * 3 + kw]);
    }
    wt[(long)co * 576 + tap * 64 + ci] = v;
}

// --- enc1 weight pack: wb1[co][k64], k=(kh*4+kw)*3+ci (48 real, 16 zero)
__global__ void wb1_kernel(const float* __restrict__ w, bfraw* __restrict__ wt) {
    int i = blockIdx.x * 256 + threadIdx.x;
    if (i >= 4096) return;
    int k = i & 63, co = i >> 6;
    bfraw v = 0;
    if (k < 48) {
        int ci = k % 3, tap = k / 3, kh = tap >> 2, kw = tap & 3;
        v = f2bf(w[(((long)co * 3 + ci) * 4 + kh) * 4 + kw]);
    }
    wt[(long)co * 64 + k] = v;
}

// --- enc1 im2col: x NCHW fp32 -> A0[pos][64] bf16 (48 patch vals + 16 zeros)
__global__ __launch_bounds__(256) void xpack_kernel(const float* __restrict__ x,
                                                    bfraw* __restrict__ a0) {
    int pos = blockIdx.x * 256 + threadIdx.x;        // 262144
    int ow = pos & 127, oh = (pos >> 7) & 127, n = pos >> 14;
    __align__(16) bfraw v[64];
#pragma unroll
    for (int i = 0; i < 64; ++i) v[i] = 0;
#pragma unroll
    for (int kh = 0; kh < 4; ++kh) {
        int ih = 2 * oh - 1 + kh; if ((unsigned)ih >= 256u) continue;
#pragma unroll
        for (int kw = 0; kw < 4; ++kw) {
            int iw = 2 * ow - 1 + kw; if ((unsigned)iw >= 256u) continue;
#pragma unroll
            for (int ci = 0; ci < 3; ++ci)
                v[(kh * 4 + kw) * 3 + ci] =
                    f2bf(x[(((long)n * 3 + ci) * 256 + ih) * 256 + iw]);
        }
    }
    uint4* dst = (uint4*)(a0 + (long)pos * 64);
    const uint4* src = (const uint4*)v;
#pragma unroll
    for (int i = 0; i < 8; ++i) dst[i] = src[i];
}

// --- emb row norms
__global__ void embsq_kernel(const float* __restrict__ emb, float* __restrict__ esq) {
    int k = blockIdx.x, lane = threadIdx.x;
    float s = 0.f;
    for (int d = lane; d < 256; d += 64) { float v = emb[k * 256 + d]; s += v * v; }
    for (int o = 32; o; o >>= 1) s += __shfl_down(s, o, 64);
    if (lane == 0) esq[k] = s;
}

// ---------------------------------------------------------------------------
// MFMA implicit GEMM. C[MxN] = A[MxK]*B[KxN]. 2-phase double-buffered LDS
// for A and B (R11-proven). Grid mapping:
//   TR (convT): 1D grid, xcd=bid&7 owns contiguous tiles; per tile the 4
//     parity classes adjacent: cls=(bid>>3)&3, blockM=(bid&7)*(nwg/32)+(bid>>5).
//   else: XCD-bijective blockM=(bid&7)*(nwg/8)+(bid>>3), cls=0.
// ---------------------------------------------------------------------------
template<int BM, int BN, int WM, int WN, bool TR, bool RELU, bool OUTF32, bool DUALB>
__global__ __launch_bounds__(256) void igemm_kernel(
    const bfraw* __restrict__ in, const bfraw* __restrict__ wt,
    const float* __restrict__ bias, void* __restrict__ outv,
    bfraw* __restrict__ outb, const bfraw* __restrict__ zp,
    int Hin, int Win, int Cin, int sf, int NTW, int Ksteps,
    int lw, int lh, int N, int KW, int pad,
    unsigned long long pk0, unsigned long long pk1,
    unsigned long long pk2, unsigned long long pk3)
{
    constexpr int APASS = BM / 64, BPASS = BN / 64;
    __shared__ __align__(16) bfraw ldsA[2][BM * 32];
    __shared__ __align__(16) bfraw ldsB[2][BN * 32];
    const int tid = threadIdx.x, lane = tid & 63, wv = tid >> 6;
    const int wm = wv / WN, wn = wv % WN;
    const int lrow = lane >> 2, lkof = (lane & 3) * 8;
    const int n0 = blockIdx.y * BN;
    const int Wm1 = (1 << lw) - 1, Hm1 = (1 << lh) - 1;
    // grid mapping (see header comment)
    const int bid = blockIdx.x;
    int blockM, cls;
    if (TR) {
        cls = (bid >> 3) & 3;                               // gridDim.x % 32 == 0
        blockM = (bid & 7) * ((int)gridDim.x >> 5) + (bid >> 5);
    } else {
        cls = 0;                                            // gridDim.x % 8 == 0
        blockM = (bid & 7) * ((int)gridDim.x >> 3) + (bid >> 3);
    }
    const unsigned long long pack = (cls == 0) ? pk0 : (cls == 1) ? pk1
                                  : (cls == 2) ? pk2 : pk3;
    const int py = cls >> 1, px = cls & 1;

    long baseA[APASS]; int ihb[APASS], iwb[APASS];
#pragma unroll
    for (int p = 0; p < APASS; ++p) {
        int m = p * 64 + wv * 16 + lrow;
        int pos = blockM * BM + m;
        int ow = pos & Wm1; int t = pos >> lw;
        int oh = t & Hm1;   int nb = t >> lh;
        ihb[p] = oh * sf; iwb[p] = ow * sf;
        baseA[p] = ((long)(nb * Hin + ihb[p]) * Win + iwb[p]) * (long)Cin + lkof;
    }
    long baseB[BPASS];
#pragma unroll
    for (int p = 0; p < BPASS; ++p) {
        int nl = p * 64 + wv * 16 + lrow;
        baseB[p] = (long)(n0 + nl) * ((long)NTW * Cin) + lkof;
    }

    f32x4 acc[4][4];
#pragma unroll
    for (int i = 0; i < 4; ++i)
#pragma unroll
        for (int j = 0; j < 4; ++j) acc[i][j] = (f32x4)0.f;

    int ci0 = 0, tslot = 0, dy, dx, wk;
    if (TR) {
        unsigned e = (unsigned)pack & 0xFFFFu;
        dy = (int)((e >> 8) & 3) - 1; dx = (int)((e >> 4) & 3) - 1; wk = (int)(e & 15u);
    } else { dy = -pad; dx = -pad; wk = 0; }

    const int quad = lane >> 4, r16 = lane & 15;

    // ---- stage helper (issues APASS+BPASS async loads into buf) ----
    auto stage = [&](int buf) {
        long offA = ((long)(dy * Win + dx)) * Cin + ci0;
        long offB = (long)wk * Cin + ci0;
#pragma unroll
        for (int p = 0; p < APASS; ++p) {
            int ih = ihb[p] + dy, iw = iwb[p] + dx;
            bool ok = ((unsigned)ih < (unsigned)Hin) & ((unsigned)iw < (unsigned)Win);
            const bfraw* g = ok ? (in + baseA[p] + offA) : (zp + lkof);
            gl_lds16(g, &ldsA[buf][(p * 64 + wv * 16) * 32]);
        }
#pragma unroll
        for (int p = 0; p < BPASS; ++p)
            gl_lds16(wt + baseB[p] + offB, &ldsB[buf][(p * 64 + wv * 16) * 32]);
    };
    auto advance = [&]() {
        ci0 += 32;
        if (ci0 == Cin) {
            ci0 = 0; ++tslot;
            if (TR) {
                unsigned e = (unsigned)(pack >> ((tslot & 3) * 16)) & 0xFFFFu;
                dy = (int)((e >> 8) & 3) - 1; dx = (int)((e >> 4) & 3) - 1; wk = (int)(e & 15u);
            } else { ++wk; ++dx; if (dx == KW - pad) { dx = -pad; ++dy; } }
        }
    };

    // prologue: stage K-step 0
    stage(0); advance();
    __syncthreads();                         // vmcnt(0): buf0 resident

    for (int ks = 0; ks < Ksteps; ++ks) {
        const int cur = ks & 1;
        if (ks + 1 < Ksteps) { stage(cur ^ 1); advance(); }   // issue-early
        s16x8 af[4], bf[4];
#pragma unroll
        for (int i = 0; i < 4; ++i)
            af[i] = *(const s16x8*)&ldsA[cur][(wm * 64 + i * 16 + r16) * 32 + quad * 8];
#pragma unroll
        for (int j = 0; j < 4; ++j)
            bf[j] = *(const s16x8*)&ldsB[cur][(wn * 64 + j * 16 + r16) * 32 + quad * 8];
#pragma unroll
        for (int i = 0; i < 4; ++i)
#pragma unroll
            for (int j = 0; j < 4; ++j)
                acc[i][j] = __builtin_amdgcn_mfma_f32_16x16x32_bf16(af[i], bf[j], acc[i][j], 0, 0, 0);
        __syncthreads();                     // drain stage(ks+1) + guard buf reuse
    }

#pragma unroll
    for (int j = 0; j < 4; ++j) {
        int col = wn * 64 + j * 16 + r16; int ng = n0 + col;
        float bv = bias[ng];
#pragma unroll
        for (int i = 0; i < 4; ++i) {
            int mb = wm * 64 + i * 16 + quad * 4;
#pragma unroll
            for (int r = 0; r < 4; ++r) {
                int pos2 = blockM * BM + mb + r;
                long oaddr;
                if (TR) {
                    int ow2 = pos2 & Wm1; int t = pos2 >> lw;
                    int oh2 = t & Hm1;    int nb = t >> lh;
                    int oh = 2 * oh2 + py, ow = 2 * ow2 + px;
                    oaddr = ((long)(((nb << (lh + 1)) + oh) << (lw + 1)) + ow) * N + ng;
                } else {
                    oaddr = (long)pos2 * N + ng;
                }
                float v = acc[i][j][r] + bv;
                if (RELU) v = fmaxf(v, 0.f);
                if (OUTF32) {
                    ((float*)outv)[oaddr] = v;
                    if (DUALB) outb[oaddr] = f2bf(v);
                } else {
                    ((bfraw*)outv)[oaddr] = f2bf(v);
                }
            }
        }
    }
}

// ---------------------------------------------------------------------------
// dec2m: convT k3 s1 p1, 64->3ch via MFMA. Block = 16x16 output tile (grid
// 4096), 4 waves. Halo 18x18x64 staged once (px&7 sub-slot swizzle, as R6
// dec2). B = wb2[16][576] staged once, col&7 swizzled. Then 18 ksteps
// (tap, ci-half) x (4 A ds_read_b128 + 1 B read + 4 mfma_16x16x32_bf16)
// per wave, no barriers. A-frag: row r16 -> px (wv*4+i, r16); k = quad*8.
// C: row quad*4+r, col r16 = co. Lanes r16<3 write fp32 NCHW planes + bias.
// ---------------------------------------------------------------------------
__global__ __launch_bounds__(256) void dec2m_kernel(
    const bfraw* __restrict__ in, const bfraw* __restrict__ wb2,
    const float* __restrict__ bias, float* __restrict__ out,
    const bfraw* __restrict__ zp) {
    __shared__ __align__(16) bfraw tile[18 * 18 * 64];   // 41,472 B
    __shared__ __align__(16) bfraw ldsB[16 * 576];       // 18,432 B
    const int tid = threadIdx.x;
    const int b = blockIdx.x;
    const int n = b >> 8, t8 = b & 255;
    const int r0 = (t8 >> 4) * 16, c0 = (t8 & 15) * 16;
    const int wv = tid >> 6, lane = tid & 63;
    const int quad = lane >> 4, r16 = lane & 15;
    const long nbase = (long)n * 65536;

    // ---- stage halo: 2592 segs of 16B (identical to R6 dec2) ----
#pragma unroll
    for (int k = 0; k < 10; ++k) {
        int t = k * 256 + tid;
        int px = t >> 3, d = t & 7;
        int pr = px / 18, pc = px - pr * 18;
        int ih = r0 - 1 + pr, iw = c0 - 1 + pc;
        bool ok = ((unsigned)ih < 256u) & ((unsigned)iw < 256u);
        int s = d ^ (px & 7);                            // pre-swizzled source sub-seg
        const bfraw* g = ok ? in + ((nbase + (long)ih * 256 + iw) << 6) + s * 8 : zp;
        gl_lds16(g, &tile[(k * 256 + wv * 64) * 8]);
    }
    if (tid < 32) {
        int t = 2560 + tid;
        int px = t >> 3, d = t & 7;
        int pr = px / 18, pc = px - pr * 18;
        int ih = r0 - 1 + pr, iw = c0 - 1 + pc;
        bool ok = ((unsigned)ih < 256u) & ((unsigned)iw < 256u);
        int s = d ^ (px & 7);
        const bfraw* g = ok ? in + ((nbase + (long)ih * 256 + iw) << 6) + s * 8 : zp;
        gl_lds16(g, &tile[2560 * 8]);
    }
    // ---- stage B: 1152 segs of 16B; LDS slot (c,s) <- global seg s^(c&7) ----
#pragma unroll
    for (int k = 0; k < 4; ++k) {
        int t = k * 256 + tid;
        int c = t / 72, s = t - c * 72;
        gl_lds16(wb2 + (long)c * 576 + ((s ^ (c & 7)) << 3), &ldsB[(k * 256 + wv * 64) * 8]);
    }
    if (tid < 128) {
        int t = 1024 + tid;
        int c = t / 72, s = t - c * 72;
        gl_lds16(wb2 + (long)c * 576 + ((s ^ (c & 7)) << 3), &ldsB[(1024 + wv * 64) * 8]);
    }
    __syncthreads();   // drains vmcnt: halo + B resident

    f32x4 acc[4];
#pragma unroll
    for (int i = 0; i < 4; ++i) acc[i] = (f32x4)0.f;

    int qb[4];
#pragma unroll
    for (int i = 0; i < 4; ++i) qb[i] = (wv * 4 + i + 1) * 18 + (r16 + 1);

#pragma unroll
    for (int ks = 0; ks < 18; ++ks) {
        const int tap = ks >> 1, h = ks & 1;
        const int dy = tap / 3 - 1, dx = tap % 3 - 1;
        s16x8 bfr = *(const s16x8*)&ldsB[r16 * 576 + (((ks * 4 + quad) ^ (r16 & 7)) << 3)];
        s16x8 afr[4];
#pragma unroll
        for (int i = 0; i < 4; ++i) {
            int q = qb[i] + dy * 18 + dx;
            afr[i] = *(const s16x8*)&tile[(q << 6) + ((((h << 2) + quad) ^ (q & 7)) << 3)];
        }
#pragma unroll
        for (int i = 0; i < 4; ++i)
            acc[i] = __builtin_amdgcn_mfma_f32_16x16x32_bf16(afr[i], bfr, acc[i], 0, 0, 0);
    }

    // ---- epilogue: col r16 = co (0..2 real); row = quad*4 + r ----
    if (r16 < 3) {
        float bv = bias[r16];
        float* plane = out + (((long)(n * 3 + r16)) << 16);
#pragma unroll
        for (int i = 0; i < 4; ++i) {
            int oh = r0 + wv * 4 + i;
#pragma unroll
            for (int r = 0; r < 4; ++r) {
                int ow = c0 + quad * 4 + r;
                plane[((long)oh << 8) + ow] = acc[i][r] + bv;
            }
        }
    }
}

// ---------------------------------------------------------------------------
// VQ partial argmin: grid (512 row-blocks x 4 code-chunks). Block = 128 rows
// x 128 codes, K=256 via 8 ksteps of the R6-proven 2-barrier staged loop
// (18.6 KB LDS -> 4 blocks/CU). dist = ||e||^2 - 2*S; per-lane strict-< in
// ascending code order, 16-lane shuffle reduce, cross-half LDS merge, then
// ONE (val,key) partial per row to pb[chunk*65536 + pos].
// ---------------------------------------------------------------------------
__global__ __launch_bounds__(256) void vqm_kernel(
    const bfraw* __restrict__ zeb, const bfraw* __restrict__ embB,
    const float* __restrict__ esq, float2* __restrict__ pb)
{
    __shared__ __align__(16) bfraw ldsA[128 * 32];
    __shared__ __align__(16) bfraw ldsB[128 * 32];
    __shared__ float sEsq[128];
    __shared__ float sVal[2][128];
    __shared__ int   sKey[2][128];
    const int tid = threadIdx.x, lane = tid & 63, wv = tid >> 6;
    const int wm = wv >> 1, wn = wv & 1;
    const int lrow = lane >> 2, lkof = (lane & 3) * 8;
    const int quad = lane >> 4, r16 = lane & 15;
    const int posBase = blockIdx.x * 128;
    const int codeBase = blockIdx.y * 128;

    if (tid < 128) sEsq[tid] = esq[codeBase + tid];

    const long baseA0 = (long)(posBase + wv * 16 + lrow) * 256 + lkof;
    const long baseA1 = baseA0 + 64 * 256;
    const long baseB0 = (long)(codeBase + wv * 16 + lrow) * 256 + lkof;
    const long baseB1 = baseB0 + 64 * 256;

    f32x4 acc[4][4];
#pragma unroll
    for (int i = 0; i < 4; ++i)
#pragma unroll
        for (int j = 0; j < 4; ++j) acc[i][j] = (f32x4)0.f;

    for (int k = 0; k < 8; ++k) {
        gl_lds16(zeb + baseA0 + k * 32, &ldsA[(wv * 16) * 32]);
        gl_lds16(zeb + baseA1 + k * 32, &ldsA[(64 + wv * 16) * 32]);
        gl_lds16(embB + baseB0 + k * 32, &ldsB[(wv * 16) * 32]);
        gl_lds16(embB + baseB1 + k * 32, &ldsB[(64 + wv * 16) * 32]);
        __syncthreads();
        s16x8 af[4], bf[4];
#pragma unroll
        for (int i = 0; i < 4; ++i)
            af[i] = *(const s16x8*)&ldsA[(wm * 64 + i * 16 + r16) * 32 + quad * 8];
#pragma unroll
        for (int j = 0; j < 4; ++j)
            bf[j] = *(const s16x8*)&ldsB[(wn * 64 + j * 16 + r16) * 32 + quad * 8];
#pragma unroll
        for (int i = 0; i < 4; ++i)
#pragma unroll
            for (int j = 0; j < 4; ++j)
                acc[i][j] = __builtin_amdgcn_mfma_f32_16x16x32_bf16(af[i], bf[j], acc[i][j], 0, 0, 0);
        __syncthreads();
    }

    // epilogue: dist + argmin. C row = i*16 + quad*4 + r (in wm half), col = r16.
#pragma unroll
    for (int i = 0; i < 4; ++i) {
#pragma unroll
        for (int r = 0; r < 4; ++r) {
            float v = 1e30f; int kk = 1 << 30;
#pragma unroll
            for (int j = 0; j < 4; ++j) {           // j ascending -> codes ascending
                int code = codeBase + wn * 64 + j * 16 + r16;
                float d = sEsq[wn * 64 + j * 16 + r16] - 2.f * acc[i][j][r];
                if (d < v) { v = d; kk = code; }    // strict < keeps first index
            }
#pragma unroll
            for (int m = 1; m < 16; m <<= 1) {
                float ov = __shfl_xor(v, m, 64);
                int   ok = __shfl_xor(kk, m, 64);
                if (ov < v || (ov == v && ok < kk)) { v = ov; kk = ok; }
            }
            if (r16 == 0) {
                int localRow = wm * 64 + i * 16 + quad * 4 + r;
                sVal[wn][localRow] = v;
                sKey[wn][localRow] = kk;
            }
        }
    }
    __syncthreads();
    // merge halves: one (val,key) partial per row for this code chunk
    if (tid < 128) {
        float v0 = sVal[0][tid]; int k0 = sKey[0][tid];
        float v1 = sVal[1][tid]; int k1 = sKey[1][tid];
        bool take1 = (v1 < v0) || (v1 == v0 && k1 < k0);
        float2 p; p.x = take1 ? v1 : v0;
        p.y = __int_as_float(take1 ? k1 : k0);
        pb[(long)blockIdx.y * 65536 + posBase + tid] = p;
    }
}

// ---------------------------------------------------------------------------
// VQ merge + gather: 2048 blocks x 32 px. Merge the 4 chunk partials
// (ascending chunk order + key tie-break -> global first-min), one hist
// atomic per px, then stream zq (fp32) + zqb (bf16) at full write BW.
// ---------------------------------------------------------------------------
__global__ __launch_bounds__(256) void vqg_kernel(
    const float2* __restrict__ pb, const float* __restrict__ emb,
    float* __restrict__ zq, bfraw* __restrict__ zqb, int* __restrict__ hist)
{
    __shared__ int sIdxL[32];
    const int tid = threadIdx.x;
    const int posBase = blockIdx.x * 32;
    if (tid < 32) {
        float bv = 1e30f; int bk = 1 << 30;
#pragma unroll
        for (int c = 0; c < 4; ++c) {
            float2 p = pb[(long)c * 65536 + posBase + tid];
            int k = __float_as_int(p.y);
            if (p.x < bv || (p.x == bv && k < bk)) { bv = p.x; bk = k; }
        }
        sIdxL[tid] = bk;
        atomicAdd(&hist[bk], 1);
    }
    __syncthreads();
    const float4* emb4 = (const float4*)emb;
    float4*  zq4  = (float4*)(zq + (long)posBase * 256);
    ushort4* zqb4 = (ushort4*)(zqb + (long)posBase * 256);
#pragma unroll
    for (int it = 0; it < 8; ++it) {
        int i2 = it * 256 + tid;
        int p = i2 >> 6, c = i2 & 63;
        float4 vv = emb4[(long)sIdxL[p] * 64 + c];
        zq4[i2] = vv;
        ushort4 u; u.x = f2bf(vv.x); u.y = f2bf(vv.y); u.z = f2bf(vv.z); u.w = f2bf(vv.w);
        zqb4[i2] = u;
    }
}

// --- perplexity
__global__ void ppl_kernel(const int* __restrict__ hist, float* __restrict__ outp) {
    __shared__ float red[512];
    int t = threadIdx.x;
    float p = (float)hist[t] * (1.0f / 65536.0f);
    red[t] = p * logf(p + 1e-10f);
    __syncthreads();
    for (int s = 256; s; s >>= 1) { if (t < s) red[t] += red[t + s]; __syncthreads(); }
    if (t == 0) *outp = expf(-red[0]);
}

// host: pack convT parity-class tap table (4 entries x 16 bits)
static unsigned long long packFor(int py, int px) {
    unsigned long long pk = 0; int s = 0;
    for (int kh = 0; kh < 4; ++kh) {
        if (((py + 1 - kh) & 1) != 0) continue;
        int dy = (py + 1 - kh) / 2;
        for (int kw = 0; kw < 4; ++kw) {
            if (((px + 1 - kw) & 1) != 0) continue;
            int dx = (px + 1 - kw) / 2;
            unsigned e = ((unsigned)(dy + 1) << 8) | ((unsigned)(dx + 1) << 4) | (unsigned)(kh * 4 + kw);
            pk |= (unsigned long long)e << (16 * s); ++s;
        }
    }
    return pk;
}

extern "C" void kernel_launch(void* const* d_in, const int* in_sizes, int n_in,
                              void* d_out, int out_size, void* d_ws, size_t ws_size,
                              hipStream_t stream) {
    const float* x       = (const float*)d_in[0];
    const float* w_enc1  = (const float*)d_in[1];
    const float* b_enc1  = (const float*)d_in[2];
    const float* w_enc2  = (const float*)d_in[3];
    const float* b_enc2  = (const float*)d_in[4];
    const float* w_prevq = (const float*)d_in[5];
    const float* b_prevq = (const float*)d_in[6];
    const float* emb     = (const float*)d_in[7];
    const float* w_post  = (const float*)d_in[8];
    const float* b_post  = (const float*)d_in[9];
    const float* w_dec1  = (const float*)d_in[10];
    const float* b_dec1  = (const float*)d_in[11];
    const float* w_dec2  = (const float*)d_in[12];
    const float* b_dec2  = (const float*)d_in[13];

    float* out = (float*)d_out;
    float* xr  = out;                     // 3,145,728
    float* ze  = out + 3145728;           // 16,777,216
    float* zq  = ze + 16777216;           // 16,777,216
    float* ppl = zq + 16777216;           // 1

    // ---- workspace carve (bytes) ----
    char* W = (char*)d_ws;
    float* esq  = (float*)(W + 24576);      // 2 KB
    int*   hist = (int*)(W + 28672);        // 2 KB
    bfraw* zp   = (bfraw*)(W + 32768);      // zero page, 256 B
    bfraw* wb2  = (bfraw*)(W + 262144);     // dec2 bf16 [16][576]       18.4 KB
    bfraw* w2b  = (bfraw*)(W + 560128);     // enc2  bf16 [co][16][64]   256 KB
    bfraw* w3b  = (bfraw*)(W + 822272);     // prevq bf16 [co][9][128]   576 KB
    bfraw* wpb  = (bfraw*)(W + 1412096);    // post  bf16 [co][16][256]  1 MB
    bfraw* wd1b = (bfraw*)(W + 2460672);    // dec1  bf16 [co][16][128]  256 KB
    bfraw* wb1  = (bfraw*)(W + 2722816);    // enc1  bf16 [co][64]        8 KB
    bfraw* embB = (bfraw*)(W + 2736128);    // emb   bf16 [512][256]    256 KB
    // bufX (128 MiB @ +4 MiB): sequential lifetimes
    //   a0 [0,33.5M) -> h2 [0,16.8M) -> zeb [16.8M,50.3M) -> zqb [50.3M,83.9M)
    //   -> ddec1 [0,134.2M). pb (2 MB) lives at bufX+0 during VQ (a0/h2 dead).
    char* bufX = W + 4194304;
    bfraw* a0    = (bfraw*)bufX;
    bfraw* h2    = (bfraw*)bufX;
    bfraw* zeb   = (bfraw*)(bufX + 16777216);
    bfraw* zqb   = (bfraw*)(bufX + 50331648);
    bfraw* ddec1 = (bfraw*)bufX;
    float2* pb   = (float2*)bufX;           // 4*65536*8 B = 2 MB (VQ partials)
    // bufY (67.1 MB): dpost
    bfraw* dpost = (bfraw*)(W + 138412032);
    bfraw* h1    = (bfraw*)ze;              // alias: h1 dies before prevq writes z_e

    // ---- weight transforms + precomputes ----
    wb2_kernel<<<36, 256, 0, stream>>>(w_dec2, wb2);
    wb1_kernel<<<16, 256, 0, stream>>>(w_enc1, wb1);
    wtb_kernel<<<512, 256, 0, stream>>>(w_enc2, w2b, 128, 64, 4, 4, 0);
    wtb_kernel<<<1152, 256, 0, stream>>>(w_prevq, w3b, 256, 128, 3, 3, 0);
    wtb_kernel<<<2048, 256, 0, stream>>>(w_post, wpb, 128, 256, 4, 4, 1);
    wtb_kernel<<<512, 256, 0, stream>>>(w_dec1, wd1b, 64, 128, 4, 4, 1);
    wtb_kernel<<<512, 256, 0, stream>>>(emb, embB, 512, 256, 1, 1, 0);
    embsq_kernel<<<512, 64, 0, stream>>>(emb, esq);
    hipMemsetAsync(hist, 0, 512 * sizeof(int), stream);
    hipMemsetAsync(zp, 0, 256, stream);

    // ---- encoder ----
    xpack_kernel<<<1024, 256, 0, stream>>>(x, a0);
    igemm_kernel<256, 64, 4, 1, false, true, false, false><<<dim3(1024, 1, 1), 256, 0, stream>>>(
        a0, wb1, b_enc1, h1, nullptr, zp, 512, 512, 64, 1, 1, 2, 9, 9, 64, 1, 0,
        0ULL, 0ULL, 0ULL, 0ULL);
    igemm_kernel<128, 128, 2, 2, false, true, false, false><<<dim3(512, 1, 1), 256, 0, stream>>>(
        h1, w2b, b_enc2, h2, nullptr, zp, 128, 128, 64, 2, 16, 32, 6, 6, 128, 4, 1,
        0ULL, 0ULL, 0ULL, 0ULL);
    // prevq: dual output ze fp32 + zeb bf16
    igemm_kernel<128, 128, 2, 2, false, false, true, true><<<dim3(512, 2, 1), 256, 0, stream>>>(
        h2, w3b, b_prevq, ze, zeb, zp, 64, 64, 128, 1, 9, 36, 6, 6, 256, 3, 1,
        0ULL, 0ULL, 0ULL, 0ULL);

    // ---- VQ: partial argmin (512x4 blocks) -> merge+gather (2048 blocks) ----
    vqm_kernel<<<dim3(512, 4), 256, 0, stream>>>(zeb, embB, esq, pb);
    vqg_kernel<<<2048, 256, 0, stream>>>(pb, emb, zq, zqb, hist);
    ppl_kernel<<<1, 512, 0, stream>>>(hist, ppl);

    // ---- decoder: 4 parity classes class-coalesced in a 1D grid ----
    igemm_kernel<128, 128, 2, 2, true, false, false, false><<<dim3(2048, 1, 1), 256, 0, stream>>>(
        zqb, wpb, b_post, dpost, nullptr, zp, 64, 64, 256, 1, 16, 32, 6, 6, 128, 4, 1,
        packFor(0, 0), packFor(0, 1), packFor(1, 0), packFor(1, 1));
    igemm_kernel<256, 64, 4, 1, true, true, false, false><<<dim3(4096, 1, 1), 256, 0, stream>>>(
        dpost, wd1b, b_dec1, ddec1, nullptr, zp, 128, 128, 128, 1, 16, 16, 7, 7, 64, 4, 1,
        packFor(0, 0), packFor(0, 1), packFor(1, 0), packFor(1, 1));
    dec2m_kernel<<<4096, 256, 0, stream>>>(ddec1, wb2, b_dec2, xr, zp);
}

// Round 11
// 696.989 us; speedup vs baseline: 30.7306x; 1.0068x over previous
//
#include <hip/hip_runtime.h>
#include <stdint.h>

// ---------------------------------------------------------------------------
// VQ-VAE forward on MI355X. Round 15: igemm VALU-hoist + 4-way LDS swizzle.
// R14's dec1: FETCH 500->38MB (class-coalescing worked), now VALU/addressing
// bound: per-kstep addr recompute (~1280cyc/wave) == MFMA time, VALUBusy 43%
// vs MfmaUtil 24%, plus 8.4M LDS bank-conflict cycles (64B row stride ->
// 8-way alias on b128 fragment reads). R15: (1) per-lane resolved pointers
// pA/pB advanced +=32/kstep, full tap recompute only on tap change (retap);
// zp page 1KB for masked-row drift. (2) both-sides bank swizzle: stage
// global sub-chunk (lane&3)^(lrow&3) -> linear LDS; read slot quad^(r16&3).
// 8-way -> 4-way. Bit-identical numerics. Rest unchanged from R14.
// ---------------------------------------------------------------------------

typedef unsigned short bfraw;
typedef __attribute__((ext_vector_type(8))) short s16x8;
typedef __attribute__((ext_vector_type(4))) float f32x4;

__device__ __forceinline__ float bflo(unsigned int u) {
    union { unsigned int i; float f; } v; v.i = u << 16; return v.f;
}
__device__ __forceinline__ float bfhi(unsigned int u) {
    union { unsigned int i; float f; } v; v.i = u & 0xFFFF0000u; return v.f;
}
__device__ __forceinline__ bfraw f2bf(float f) {
    union { float f; unsigned int i; } v; v.f = f;
    unsigned int r = v.i + 0x7FFFu + ((v.i >> 16) & 1u);   // RNE
    return (bfraw)(r >> 16);
}

// async 16B global->LDS. LDS dest: wave-uniform base + lane*16; global src per-lane.
__device__ __forceinline__ void gl_lds16(const void* g, void* l) {
    auto gp = reinterpret_cast<const __attribute__((address_space(1))) unsigned int*>(
        reinterpret_cast<uintptr_t>(g));
    auto lp = reinterpret_cast<__attribute__((address_space(3))) unsigned int*>(
        reinterpret_cast<uintptr_t>(l));
    __builtin_amdgcn_global_load_lds(gp, lp, 16, 0, 0);
}

// --- weight transform (bf16, [co][tap][ci]) for MFMA convs (B as [n][k]);
//     with KH=KW=1 also converts emb[512][256] to bf16 B layout.
__global__ void wtb_kernel(const float* __restrict__ w, bfraw* __restrict__ wt,
                           int Cout, int Cin, int KH, int KW, int transposed) {
    int n = Cout * Cin * KH * KW;
    int NT = KH * KW;
    for (int i = blockIdx.x * blockDim.x + threadIdx.x; i < n; i += gridDim.x * blockDim.x) {
        int ci = i % Cin; int t = i / Cin;
        int tap = t % NT; int co = t / NT;
        int kh = tap / KW, kw = tap % KW;
        float v = transposed ? w[(((long)ci * Cout + co) * KH + kh) * KW + kw]
                             : w[(((long)co * Cin + ci) * KH + kh) * KW + kw];
        wt[i] = f2bf(v);
    }
}

// --- dec2 weight pack: wb2[16][576] bf16, B[co][tap*64+ci]; rows 3..15 zero.
//     convT k3 p1 == conv with wf[co][ci][kh'][kw'] = w[ci][co][2-kh'][2-kw'].
__global__ void wb2_kernel(const float* __restrict__ w, bfraw* __restrict__ wt) {
    int i = blockIdx.x * 256 + threadIdx.x;   // 9216 = 16*576
    if (i >= 9216) return;
    int ci = i & 63; int t = i >> 6;          // t = co*9 + tap
    int tap = t % 9, co = t / 9;
    bfraw v = 0;
    if (co < 3) {
        int kh = 2 - tap / 3, kw = 2 - tap % 3;
        v = f2bf(w[(((long)ci * 3 + co) * 3 + kh) * 3 + kw]);
    }
    wt[(long)co * 576 + tap * 64 + ci] = v;
}

// --- enc1 weight pack: wb1[co][k64], k=(kh*4+kw)*3+ci (48 real, 16 zero)
__global__ void wb1_kernel(const float* __restrict__ w, bfraw* __restrict__ wt) {
    int i = blockIdx.x * 256 + threadIdx.x;
    if (i >= 4096) return;
    int k = i & 63, co = i >> 6;
    bfraw v = 0;
    if (k < 48) {
        int ci = k % 3, tap = k / 3, kh = tap >> 2, kw = tap & 3;
        v = f2bf(w[(((long)co * 3 + ci) * 4 + kh) * 4 + kw]);
    }
    wt[(long)co * 64 + k] = v;
}

// --- enc1 im2col: x NCHW fp32 -> A0[pos][64] bf16 (48 patch vals + 16 zeros)
__global__ __launch_bounds__(256) void xpack_kernel(const float* __restrict__ x,
                                                    bfraw* __restrict__ a0) {
    int pos = blockIdx.x * 256 + threadIdx.x;        // 262144
    int ow = pos & 127, oh = (pos >> 7) & 127, n = pos >> 14;
    __align__(16) bfraw v[64];
#pragma unroll
    for (int i = 0; i < 64; ++i) v[i] = 0;
#pragma unroll
    for (int kh = 0; kh < 4; ++kh) {
        int ih = 2 * oh - 1 + kh; if ((unsigned)ih >= 256u) continue;
#pragma unroll
        for (int kw = 0; kw < 4; ++kw) {
            int iw = 2 * ow - 1 + kw; if ((unsigned)iw >= 256u) continue;
#pragma unroll
            for (int ci = 0; ci < 3; ++ci)
                v[(kh * 4 + kw) * 3 + ci] =
                    f2bf(x[(((long)n * 3 + ci) * 256 + ih) * 256 + iw]);
        }
    }
    uint4* dst = (uint4*)(a0 + (long)pos * 64);
    const uint4* src = (const uint4*)v;
#pragma unroll
    for (int i = 0; i < 8; ++i) dst[i] = src[i];
}

// --- emb row norms
__global__ void embsq_kernel(const float* __restrict__ emb, float* __restrict__ esq) {
    int k = blockIdx.x, lane = threadIdx.x;
    float s = 0.f;
    for (int d = lane; d < 256; d += 64) { float v = emb[k * 256 + d]; s += v * v; }
    for (int o = 32; o; o >>= 1) s += __shfl_down(s, o, 64);
    if (lane == 0) esq[k] = s;
}

// ---------------------------------------------------------------------------
// MFMA implicit GEMM. C[MxN] = A[MxK]*B[KxN]. 2-phase double-buffered LDS.
// Addressing: per-lane resolved pointers pA/pB, +=32 elems per kstep; full
// (dy,dx,wk)+bounds recompute only on tap change (retap). Bank swizzle:
// stage loads global sub-chunk (lane&3)^(lrow&3) into linear LDS; fragment
// reads use slot quad^(r16&3) (8-way -> 4-way). Grid mapping:
//   TR: cls=(bid>>3)&3, blockM=(bid&7)*(nwg/32)+(bid>>5)  (class-coalesced)
//   else: blockM=(bid&7)*(nwg/8)+(bid>>3), cls=0.
// ---------------------------------------------------------------------------
template<int BM, int BN, int WM, int WN, bool TR, bool RELU, bool OUTF32, bool DUALB>
__global__ __launch_bounds__(256) void igemm_kernel(
    const bfraw* __restrict__ in, const bfraw* __restrict__ wt,
    const float* __restrict__ bias, void* __restrict__ outv,
    bfraw* __restrict__ outb, const bfraw* __restrict__ zp,
    int Hin, int Win, int Cin, int sf, int NTW, int Ksteps,
    int lw, int lh, int N, int KW, int pad,
    unsigned long long pk0, unsigned long long pk1,
    unsigned long long pk2, unsigned long long pk3)
{
    constexpr int APASS = BM / 64, BPASS = BN / 64;
    __shared__ __align__(16) bfraw ldsA[2][BM * 32];
    __shared__ __align__(16) bfraw ldsB[2][BN * 32];
    const int tid = threadIdx.x, lane = tid & 63, wv = tid >> 6;
    const int wm = wv / WN, wn = wv % WN;
    const int lrow = lane >> 2;
    const int lkofs = (((lane & 3) ^ (lrow & 3))) * 8;     // swizzled source sub-chunk
    const int n0 = blockIdx.y * BN;
    const int Wm1 = (1 << lw) - 1, Hm1 = (1 << lh) - 1;
    const int bid = blockIdx.x;
    int blockM, cls;
    if (TR) {
        cls = (bid >> 3) & 3;                               // gridDim.x % 32 == 0
        blockM = (bid & 7) * ((int)gridDim.x >> 5) + (bid >> 5);
    } else {
        cls = 0;                                            // gridDim.x % 8 == 0
        blockM = (bid & 7) * ((int)gridDim.x >> 3) + (bid >> 3);
    }
    const unsigned long long pack = (cls == 0) ? pk0 : (cls == 1) ? pk1
                                  : (cls == 2) ? pk2 : pk3;
    const int py = cls >> 1, px = cls & 1;

    long baseA[APASS]; int ihb[APASS], iwb[APASS];
#pragma unroll
    for (int p = 0; p < APASS; ++p) {
        int m = p * 64 + wv * 16 + lrow;
        int pos = blockM * BM + m;
        int ow = pos & Wm1; int t = pos >> lw;
        int oh = t & Hm1;   int nb = t >> lh;
        ihb[p] = oh * sf; iwb[p] = ow * sf;
        baseA[p] = ((long)(nb * Hin + ihb[p]) * Win + iwb[p]) * (long)Cin + lkofs;
    }
    long baseB[BPASS];
#pragma unroll
    for (int p = 0; p < BPASS; ++p) {
        int nl = p * 64 + wv * 16 + lrow;
        baseB[p] = (long)(n0 + nl) * ((long)NTW * Cin) + lkofs;
    }

    f32x4 acc[4][4];
#pragma unroll
    for (int i = 0; i < 4; ++i)
#pragma unroll
        for (int j = 0; j < 4; ++j) acc[i][j] = (f32x4)0.f;

    int ci0 = 0, tslot = 0, dy, dx, wk;
    if (TR) {
        unsigned e = (unsigned)pack & 0xFFFFu;
        dy = (int)((e >> 8) & 3) - 1; dx = (int)((e >> 4) & 3) - 1; wk = (int)(e & 15u);
    } else { dy = -pad; dx = -pad; wk = 0; }

    const int quad = lane >> 4, r16 = lane & 15;
    const int rslot = ((quad ^ (r16 & 3)) << 3);           // read sub-chunk (bf16 elems)

    const bfraw* pA[APASS];
    const bfraw* pB[BPASS];

    // recompute resolved pointers for the current tap (dy,dx,wk); ci0 == 0
    auto retap = [&]() {
        long offA = ((long)(dy * Win + dx)) * Cin;
#pragma unroll
        for (int p = 0; p < APASS; ++p) {
            int ih = ihb[p] + dy, iw = iwb[p] + dx;
            bool ok = ((unsigned)ih < (unsigned)Hin) & ((unsigned)iw < (unsigned)Win);
            pA[p] = ok ? (in + baseA[p] + offA) : (zp + lkofs);
        }
        long offB = (long)wk * Cin;
#pragma unroll
        for (int p = 0; p < BPASS; ++p)
            pB[p] = wt + baseB[p] + offB;
    };
    auto stage = [&](int buf) {
#pragma unroll
        for (int p = 0; p < APASS; ++p)
            gl_lds16(pA[p], &ldsA[buf][(p * 64 + wv * 16) * 32]);
#pragma unroll
        for (int p = 0; p < BPASS; ++p)
            gl_lds16(pB[p], &ldsB[buf][(p * 64 + wv * 16) * 32]);
    };
    auto advance = [&]() {
        ci0 += 32;
        if (ci0 == Cin) {
            ci0 = 0; ++tslot;
            if (TR) {
                unsigned e = (unsigned)(pack >> ((tslot & 3) * 16)) & 0xFFFFu;
                dy = (int)((e >> 8) & 3) - 1; dx = (int)((e >> 4) & 3) - 1; wk = (int)(e & 15u);
            } else { ++wk; ++dx; if (dx == KW - pad) { dx = -pad; ++dy; } }
            retap();
        } else {
#pragma unroll
            for (int p = 0; p < APASS; ++p) pA[p] += 32;
#pragma unroll
            for (int p = 0; p < BPASS; ++p) pB[p] += 32;
        }
    };

    // prologue: stage K-step 0
    retap();
    stage(0); advance();
    __syncthreads();                         // vmcnt(0): buf0 resident

    for (int ks = 0; ks < Ksteps; ++ks) {
        const int cur = ks & 1;
        if (ks + 1 < Ksteps) { stage(cur ^ 1); advance(); }   // issue-early
        s16x8 af[4], bf[4];
#pragma unroll
        for (int i = 0; i < 4; ++i)
            af[i] = *(const s16x8*)&ldsA[cur][(wm * 64 + i * 16 + r16) * 32 + rslot];
#pragma unroll
        for (int j = 0; j < 4; ++j)
            bf[j] = *(const s16x8*)&ldsB[cur][(wn * 64 + j * 16 + r16) * 32 + rslot];
#pragma unroll
        for (int i = 0; i < 4; ++i)
#pragma unroll
            for (int j = 0; j < 4; ++j)
                acc[i][j] = __builtin_amdgcn_mfma_f32_16x16x32_bf16(af[i], bf[j], acc[i][j], 0, 0, 0);
        __syncthreads();                     // drain stage(ks+1) + guard buf reuse
    }

#pragma unroll
    for (int j = 0; j < 4; ++j) {
        int col = wn * 64 + j * 16 + r16; int ng = n0 + col;
        float bv = bias[ng];
#pragma unroll
        for (int i = 0; i < 4; ++i) {
            int mb = wm * 64 + i * 16 + quad * 4;
#pragma unroll
            for (int r = 0; r < 4; ++r) {
                int pos2 = blockM * BM + mb + r;
                long oaddr;
                if (TR) {
                    int ow2 = pos2 & Wm1; int t = pos2 >> lw;
                    int oh2 = t & Hm1;    int nb = t >> lh;
                    int oh = 2 * oh2 + py, ow = 2 * ow2 + px;
                    oaddr = ((long)(((nb << (lh + 1)) + oh) << (lw + 1)) + ow) * N + ng;
                } else {
                    oaddr = (long)pos2 * N + ng;
                }
                float v = acc[i][j][r] + bv;
                if (RELU) v = fmaxf(v, 0.f);
                if (OUTF32) {
                    ((float*)outv)[oaddr] = v;
                    if (DUALB) outb[oaddr] = f2bf(v);
                } else {
                    ((bfraw*)outv)[oaddr] = f2bf(v);
                }
            }
        }
    }
}

// ---------------------------------------------------------------------------
// dec2m: convT k3 s1 p1, 64->3ch via MFMA. Block = 16x16 output tile (grid
// 4096), 4 waves. Halo 18x18x64 staged once (px&7 sub-slot swizzle, as R6
// dec2). B = wb2[16][576] staged once, col&7 swizzled. Then 18 ksteps
// (tap, ci-half) x (4 A ds_read_b128 + 1 B read + 4 mfma_16x16x32_bf16)
// per wave, no barriers. A-frag: row r16 -> px (wv*4+i, r16); k = quad*8.
// C: row quad*4+r, col r16 = co. Lanes r16<3 write fp32 NCHW planes + bias.
// ---------------------------------------------------------------------------
__global__ __launch_bounds__(256) void dec2m_kernel(
    const bfraw* __restrict__ in, const bfraw* __restrict__ wb2,
    const float* __restrict__ bias, float* __restrict__ out,
    const bfraw* __restrict__ zp) {
    __shared__ __align__(16) bfraw tile[18 * 18 * 64];   // 41,472 B
    __shared__ __align__(16) bfraw ldsB[16 * 576];       // 18,432 B
    const int tid = threadIdx.x;
    const int b = blockIdx.x;
    const int n = b >> 8, t8 = b & 255;
    const int r0 = (t8 >> 4) * 16, c0 = (t8 & 15) * 16;
    const int wv = tid >> 6, lane = tid & 63;
    const int quad = lane >> 4, r16 = lane & 15;
    const long nbase = (long)n * 65536;

    // ---- stage halo: 2592 segs of 16B (identical to R6 dec2) ----
#pragma unroll
    for (int k = 0; k < 10; ++k) {
        int t = k * 256 + tid;
        int px = t >> 3, d = t & 7;
        int pr = px / 18, pc = px - pr * 18;
        int ih = r0 - 1 + pr, iw = c0 - 1 + pc;
        bool ok = ((unsigned)ih < 256u) & ((unsigned)iw < 256u);
        int s = d ^ (px & 7);                            // pre-swizzled source sub-seg
        const bfraw* g = ok ? in + ((nbase + (long)ih * 256 + iw) << 6) + s * 8 : zp;
        gl_lds16(g, &tile[(k * 256 + wv * 64) * 8]);
    }
    if (tid < 32) {
        int t = 2560 + tid;
        int px = t >> 3, d = t & 7;
        int pr = px / 18, pc = px - pr * 18;
        int ih = r0 - 1 + pr, iw = c0 - 1 + pc;
        bool ok = ((unsigned)ih < 256u) & ((unsigned)iw < 256u);
        int s = d ^ (px & 7);
        const bfraw* g = ok ? in + ((nbase + (long)ih * 256 + iw) << 6) + s * 8 : zp;
        gl_lds16(g, &tile[2560 * 8]);
    }
    // ---- stage B: 1152 segs of 16B; LDS slot (c,s) <- global seg s^(c&7) ----
#pragma unroll
    for (int k = 0; k < 4; ++k) {
        int t = k * 256 + tid;
        int c = t / 72, s = t - c * 72;
        gl_lds16(wb2 + (long)c * 576 + ((s ^ (c & 7)) << 3), &ldsB[(k * 256 + wv * 64) * 8]);
    }
    if (tid < 128) {
        int t = 1024 + tid;
        int c = t / 72, s = t - c * 72;
        gl_lds16(wb2 + (long)c * 576 + ((s ^ (c & 7)) << 3), &ldsB[(1024 + wv * 64) * 8]);
    }
    __syncthreads();   // drains vmcnt: halo + B resident

    f32x4 acc[4];
#pragma unroll
    for (int i = 0; i < 4; ++i) acc[i] = (f32x4)0.f;

    int qb[4];
#pragma unroll
    for (int i = 0; i < 4; ++i) qb[i] = (wv * 4 + i + 1) * 18 + (r16 + 1);

#pragma unroll
    for (int ks = 0; ks < 18; ++ks) {
        const int tap = ks >> 1, h = ks & 1;
        const int dy = tap / 3 - 1, dx = tap % 3 - 1;
        s16x8 bfr = *(const s16x8*)&ldsB[r16 * 576 + (((ks * 4 + quad) ^ (r16 & 7)) << 3)];
        s16x8 afr[4];
#pragma unroll
        for (int i = 0; i < 4; ++i) {
            int q = qb[i] + dy * 18 + dx;
            afr[i] = *(const s16x8*)&tile[(q << 6) + ((((h << 2) + quad) ^ (q & 7)) << 3)];
        }
#pragma unroll
        for (int i = 0; i < 4; ++i)
            acc[i] = __builtin_amdgcn_mfma_f32_16x16x32_bf16(afr[i], bfr, acc[i], 0, 0, 0);
    }

    // ---- epilogue: col r16 = co (0..2 real); row = quad*4 + r ----
    if (r16 < 3) {
        float bv = bias[r16];
        float* plane = out + (((long)(n * 3 + r16)) << 16);
#pragma unroll
        for (int i = 0; i < 4; ++i) {
            int oh = r0 + wv * 4 + i;
#pragma unroll
            for (int r = 0; r < 4; ++r) {
                int ow = c0 + quad * 4 + r;
                plane[((long)oh << 8) + ow] = acc[i][r] + bv;
            }
        }
    }
}

// ---------------------------------------------------------------------------
// VQ partial argmin: grid (512 row-blocks x 4 code-chunks). Block = 128 rows
// x 128 codes, K=256 via 8 ksteps of the R6-proven 2-barrier staged loop
// (18.6 KB LDS -> 4 blocks/CU). dist = ||e||^2 - 2*S; per-lane strict-< in
// ascending code order, 16-lane shuffle reduce, cross-half LDS merge, then
// ONE (val,key) partial per row to pb[chunk*65536 + pos].
// ---------------------------------------------------------------------------
__global__ __launch_bounds__(256) void vqm_kernel(
    const bfraw* __restrict__ zeb, const bfraw* __restrict__ embB,
    const float* __restrict__ esq, float2* __restrict__ pb)
{
    __shared__ __align__(16) bfraw ldsA[128 * 32];
    __shared__ __align__(16) bfraw ldsB[128 * 32];
    __shared__ float sEsq[128];
    __shared__ float sVal[2][128];
    __shared__ int   sKey[2][128];
    const int tid = threadIdx.x, lane = tid & 63, wv = tid >> 6;
    const int wm = wv >> 1, wn = wv & 1;
    const int lrow = lane >> 2, lkof = (lane & 3) * 8;
    const int quad = lane >> 4, r16 = lane & 15;
    const int posBase = blockIdx.x * 128;
    const int codeBase = blockIdx.y * 128;

    if (tid < 128) sEsq[tid] = esq[codeBase + tid];

    const long baseA0 = (long)(posBase + wv * 16 + lrow) * 256 + lkof;
    const long baseA1 = baseA0 + 64 * 256;
    const long baseB0 = (long)(codeBase + wv * 16 + lrow) * 256 + lkof;
    const long baseB1 = baseB0 + 64 * 256;

    f32x4 acc[4][4];
#pragma unroll
    for (int i = 0; i < 4; ++i)
#pragma unroll
        for (int j = 0; j < 4; ++j) acc[i][j] = (f32x4)0.f;

    for (int k = 0; k < 8; ++k) {
        gl_lds16(zeb + baseA0 + k * 32, &ldsA[(wv * 16) * 32]);
        gl_lds16(zeb + baseA1 + k * 32, &ldsA[(64 + wv * 16) * 32]);
        gl_lds16(embB + baseB0 + k * 32, &ldsB[(wv * 16) * 32]);
        gl_lds16(embB + baseB1 + k * 32, &ldsB[(64 + wv * 16) * 32]);
        __syncthreads();
        s16x8 af[4], bf[4];
#pragma unroll
        for (int i = 0; i < 4; ++i)
            af[i] = *(const s16x8*)&ldsA[(wm * 64 + i * 16 + r16) * 32 + quad * 8];
#pragma unroll
        for (int j = 0; j < 4; ++j)
            bf[j] = *(const s16x8*)&ldsB[(wn * 64 + j * 16 + r16) * 32 + quad * 8];
#pragma unroll
        for (int i = 0; i < 4; ++i)
#pragma unroll
            for (int j = 0; j < 4; ++j)
                acc[i][j] = __builtin_amdgcn_mfma_f32_16x16x32_bf16(af[i], bf[j], acc[i][j], 0, 0, 0);
        __syncthreads();
    }

    // epilogue: dist + argmin. C row = i*16 + quad*4 + r (in wm half), col = r16.
#pragma unroll
    for (int i = 0; i < 4; ++i) {
#pragma unroll
        for (int r = 0; r < 4; ++r) {
            float v = 1e30f; int kk = 1 << 30;
#pragma unroll
            for (int j = 0; j < 4; ++j) {           // j ascending -> codes ascending
                int code = codeBase + wn * 64 + j * 16 + r16;
                float d = sEsq[wn * 64 + j * 16 + r16] - 2.f * acc[i][j][r];
                if (d < v) { v = d; kk = code; }    // strict < keeps first index
            }
#pragma unroll
            for (int m = 1; m < 16; m <<= 1) {
                float ov = __shfl_xor(v, m, 64);
                int   ok = __shfl_xor(kk, m, 64);
                if (ov < v || (ov == v && ok < kk)) { v = ov; kk = ok; }
            }
            if (r16 == 0) {
                int localRow = wm * 64 + i * 16 + quad * 4 + r;
                sVal[wn][localRow] = v;
                sKey[wn][localRow] = kk;
            }
        }
    }
    __syncthreads();
    // merge halves: one (val,key) partial per row for this code chunk
    if (tid < 128) {
        float v0 = sVal[0][tid]; int k0 = sKey[0][tid];
        float v1 = sVal[1][tid]; int k1 = sKey[1][tid];
        bool take1 = (v1 < v0) || (v1 == v0 && k1 < k0);
        float2 p; p.x = take1 ? v1 : v0;
        p.y = __int_as_float(take1 ? k1 : k0);
        pb[(long)blockIdx.y * 65536 + posBase + tid] = p;
    }
}

// ---------------------------------------------------------------------------
// VQ merge + gather: 2048 blocks x 32 px. Merge the 4 chunk partials
// (ascending chunk order + key tie-break -> global first-min), one hist
// atomic per px, then stream zq (fp32) + zqb (bf16) at full write BW.
// ---------------------------------------------------------------------------
__global__ __launch_bounds__(256) void vqg_kernel(
    const float2* __restrict__ pb, const float* __restrict__ emb,
    float* __restrict__ zq, bfraw* __restrict__ zqb, int* __restrict__ hist)
{
    __shared__ int sIdxL[32];
    const int tid = threadIdx.x;
    const int posBase = blockIdx.x * 32;
    if (tid < 32) {
        float bv = 1e30f; int bk = 1 << 30;
#pragma unroll
        for (int c = 0; c < 4; ++c) {
            float2 p = pb[(long)c * 65536 + posBase + tid];
            int k = __float_as_int(p.y);
            if (p.x < bv || (p.x == bv && k < bk)) { bv = p.x; bk = k; }
        }
        sIdxL[tid] = bk;
        atomicAdd(&hist[bk], 1);
    }
    __syncthreads();
    const float4* emb4 = (const float4*)emb;
    float4*  zq4  = (float4*)(zq + (long)posBase * 256);
    ushort4* zqb4 = (ushort4*)(zqb + (long)posBase * 256);
#pragma unroll
    for (int it = 0; it < 8; ++it) {
        int i2 = it * 256 + tid;
        int p = i2 >> 6, c = i2 & 63;
        float4 vv = emb4[(long)sIdxL[p] * 64 + c];
        zq4[i2] = vv;
        ushort4 u; u.x = f2bf(vv.x); u.y = f2bf(vv.y); u.z = f2bf(vv.z); u.w = f2bf(vv.w);
        zqb4[i2] = u;
    }
}

// --- perplexity
__global__ void ppl_kernel(const int* __restrict__ hist, float* __restrict__ outp) {
    __shared__ float red[512];
    int t = threadIdx.x;
    float p = (float)hist[t] * (1.0f / 65536.0f);
    red[t] = p * logf(p + 1e-10f);
    __syncthreads();
    for (int s = 256; s; s >>= 1) { if (t < s) red[t] += red[t + s]; __syncthreads(); }
    if (t == 0) *outp = expf(-red[0]);
}

// host: pack convT parity-class tap table (4 entries x 16 bits)
static unsigned long long packFor(int py, int px) {
    unsigned long long pk = 0; int s = 0;
    for (int kh = 0; kh < 4; ++kh) {
        if (((py + 1 - kh) & 1) != 0) continue;
        int dy = (py + 1 - kh) / 2;
        for (int kw = 0; kw < 4; ++kw) {
            if (((px + 1 - kw) & 1) != 0) continue;
            int dx = (px + 1 - kw) / 2;
            unsigned e = ((unsigned)(dy + 1) << 8) | ((unsigned)(dx + 1) << 4) | (unsigned)(kh * 4 + kw);
            pk |= (unsigned long long)e << (16 * s); ++s;
        }
    }
    return pk;
}

extern "C" void kernel_launch(void* const* d_in, const int* in_sizes, int n_in,
                              void* d_out, int out_size, void* d_ws, size_t ws_size,
                              hipStream_t stream) {
    const float* x       = (const float*)d_in[0];
    const float* w_enc1  = (const float*)d_in[1];
    const float* b_enc1  = (const float*)d_in[2];
    const float* w_enc2  = (const float*)d_in[3];
    const float* b_enc2  = (const float*)d_in[4];
    const float* w_prevq = (const float*)d_in[5];
    const float* b_prevq = (const float*)d_in[6];
    const float* emb     = (const float*)d_in[7];
    const float* w_post  = (const float*)d_in[8];
    const float* b_post  = (const float*)d_in[9];
    const float* w_dec1  = (const float*)d_in[10];
    const float* b_dec1  = (const float*)d_in[11];
    const float* w_dec2  = (const float*)d_in[12];
    const float* b_dec2  = (const float*)d_in[13];

    float* out = (float*)d_out;
    float* xr  = out;                     // 3,145,728
    float* ze  = out + 3145728;           // 16,777,216
    float* zq  = ze + 16777216;           // 16,777,216
    float* ppl = zq + 16777216;           // 1

    // ---- workspace carve (bytes) ----
    char* W = (char*)d_ws;
    float* esq  = (float*)(W + 24576);      // 2 KB
    int*   hist = (int*)(W + 28672);        // 2 KB
    bfraw* zp   = (bfraw*)(W + 32768);      // zero page, 1 KB (pointer-drift safe)
    bfraw* wb2  = (bfraw*)(W + 262144);     // dec2 bf16 [16][576]       18.4 KB
    bfraw* w2b  = (bfraw*)(W + 560128);     // enc2  bf16 [co][16][64]   256 KB
    bfraw* w3b  = (bfraw*)(W + 822272);     // prevq bf16 [co][9][128]   576 KB
    bfraw* wpb  = (bfraw*)(W + 1412096);    // post  bf16 [co][16][256]  1 MB
    bfraw* wd1b = (bfraw*)(W + 2460672);    // dec1  bf16 [co][16][128]  256 KB
    bfraw* wb1  = (bfraw*)(W + 2722816);    // enc1  bf16 [co][64]        8 KB
    bfraw* embB = (bfraw*)(W + 2736128);    // emb   bf16 [512][256]    256 KB
    // bufX (128 MiB @ +4 MiB): sequential lifetimes
    //   a0 [0,33.5M) -> h2 [0,16.8M) -> zeb [16.8M,50.3M) -> zqb [50.3M,83.9M)
    //   -> ddec1 [0,134.2M). pb (2 MB) lives at bufX+0 during VQ (a0/h2 dead).
    char* bufX = W + 4194304;
    bfraw* a0    = (bfraw*)bufX;
    bfraw* h2    = (bfraw*)bufX;
    bfraw* zeb   = (bfraw*)(bufX + 16777216);
    bfraw* zqb   = (bfraw*)(bufX + 50331648);
    bfraw* ddec1 = (bfraw*)bufX;
    float2* pb   = (float2*)bufX;           // 4*65536*8 B = 2 MB (VQ partials)
    // bufY (67.1 MB): dpost
    bfraw* dpost = (bfraw*)(W + 138412032);
    bfraw* h1    = (bfraw*)ze;              // alias: h1 dies before prevq writes z_e

    // ---- weight transforms + precomputes ----
    wb2_kernel<<<36, 256, 0, stream>>>(w_dec2, wb2);
    wb1_kernel<<<16, 256, 0, stream>>>(w_enc1, wb1);
    wtb_kernel<<<512, 256, 0, stream>>>(w_enc2, w2b, 128, 64, 4, 4, 0);
    wtb_kernel<<<1152, 256, 0, stream>>>(w_prevq, w3b, 256, 128, 3, 3, 0);
    wtb_kernel<<<2048, 256, 0, stream>>>(w_post, wpb, 128, 256, 4, 4, 1);
    wtb_kernel<<<512, 256, 0, stream>>>(w_dec1, wd1b, 64, 128, 4, 4, 1);
    wtb_kernel<<<512, 256, 0, stream>>>(emb, embB, 512, 256, 1, 1, 0);
    embsq_kernel<<<512, 64, 0, stream>>>(emb, esq);
    hipMemsetAsync(hist, 0, 512 * sizeof(int), stream);
    hipMemsetAsync(zp, 0, 1024, stream);

    // ---- encoder ----
    xpack_kernel<<<1024, 256, 0, stream>>>(x, a0);
    igemm_kernel<256, 64, 4, 1, false, true, false, false><<<dim3(1024, 1, 1), 256, 0, stream>>>(
        a0, wb1, b_enc1, h1, nullptr, zp, 512, 512, 64, 1, 1, 2, 9, 9, 64, 1, 0,
        0ULL, 0ULL, 0ULL, 0ULL);
    igemm_kernel<128, 128, 2, 2, false, true, false, false><<<dim3(512, 1, 1), 256, 0, stream>>>(
        h1, w2b, b_enc2, h2, nullptr, zp, 128, 128, 64, 2, 16, 32, 6, 6, 128, 4, 1,
        0ULL, 0ULL, 0ULL, 0ULL);
    // prevq: dual output ze fp32 + zeb bf16
    igemm_kernel<128, 128, 2, 2, false, false, true, true><<<dim3(512, 2, 1), 256, 0, stream>>>(
        h2, w3b, b_prevq, ze, zeb, zp, 64, 64, 128, 1, 9, 36, 6, 6, 256, 3, 1,
        0ULL, 0ULL, 0ULL, 0ULL);

    // ---- VQ: partial argmin (512x4 blocks) -> merge+gather (2048 blocks) ----
    vqm_kernel<<<dim3(512, 4), 256, 0, stream>>>(zeb, embB, esq, pb);
    vqg_kernel<<<2048, 256, 0, stream>>>(pb, emb, zq, zqb, hist);
    ppl_kernel<<<1, 512, 0, stream>>>(hist, ppl);

    // ---- decoder: 4 parity classes class-coalesced in a 1D grid ----
    igemm_kernel<128, 128, 2, 2, true, false, false, false><<<dim3(2048, 1, 1), 256, 0, stream>>>(
        zqb, wpb, b_post, dpost, nullptr, zp, 64, 64, 256, 1, 16, 32, 6, 6, 128, 4, 1,
        packFor(0, 0), packFor(0, 1), packFor(1, 0), packFor(1, 1));
    igemm_kernel<256, 64, 4, 1, true, true, false, false><<<dim3(4096, 1, 1), 256, 0, stream>>>(
        dpost, wd1b, b_dec1, ddec1, nullptr, zp, 128, 128, 128, 1, 16, 16, 7, 7, 64, 4, 1,
        packFor(0, 0), packFor(0, 1), packFor(1, 0), packFor(1, 1));
    dec2m_kernel<<<4096, 256, 0, stream>>>(ddec1, wb2, b_dec2, xr, zp);
}